// Round 3
// baseline (1060.338 us; speedup 1.0000x reference)
//
#include <hip/hip_runtime.h>
#include <hip/hip_bf16.h>
#include <math.h>

#define G_   64      // B*T graphs
#define NN_  500     // nodes
#define FIN_ 32
#define HD_  128
#define C1_  256     // HEADS*HD
#define E0_  8000
#define EP_  8500    // E0 + self loops
#define TT_  16
#define NR_  2000    // B*N lstm rows

__device__ __forceinline__ float fsig(float x)  { return 1.f / (1.f + __expf(-x)); }
__device__ __forceinline__ float ftanh(float x) {
    float e = __expf(fminf(fmaxf(2.f * x, -30.f), 30.f));
    return (e - 1.f) / (e + 1.f);
}

// ---------------- CSR build (by dst) ----------------
__global__ void k_deg(const int* __restrict__ ei, int* __restrict__ deg) {
    int e = blockIdx.x * blockDim.x + threadIdx.x;
    if (e >= EP_) return;
    int dst = e < E0_ ? ei[E0_ + e] : e - E0_;
    atomicAdd(&deg[dst], 1);
}
__global__ void k_scan(const int* __restrict__ deg, int* __restrict__ rowptr, int* __restrict__ cursor) {
    if (threadIdx.x == 0 && blockIdx.x == 0) {
        int acc = 0;
        for (int i = 0; i < NN_; ++i) { rowptr[i] = acc; cursor[i] = acc; acc += deg[i]; }
        rowptr[NN_] = acc;
    }
}
__global__ void k_fill(const int* __restrict__ ei, int* __restrict__ cursor, int* __restrict__ eids) {
    int e = blockIdx.x * blockDim.x + threadIdx.x;
    if (e >= EP_) return;
    int dst = e < E0_ ? ei[E0_ + e] : e - E0_;
    int pos = atomicAdd(&cursor[dst], 1);
    eids[pos] = e;
}

// ---------------- weight transpose for LSTM: WT[k][col], k = [Whh | Wih] ----------------
__global__ void k_wt(const float* __restrict__ Whh0, const float* __restrict__ Wih0,
                     const float* __restrict__ Whh1, const float* __restrict__ Wih1,
                     float* __restrict__ WT0, float* __restrict__ WT1) {
    __shared__ float tile[32][33];
    int b = blockIdx.x;
    int layer = b >> 7; int rem = b & 127;
    int kb = rem >> 4, cbk = rem & 15;
    const float* Wh = layer ? Whh1 : Whh0;
    const float* Wi = layer ? Wih1 : Wih0;
    float* WT = layer ? WT1 : WT0;
    int k0 = kb * 32, col0 = cbk * 32;
    #pragma unroll
    for (int q = 0; q < 4; ++q) {
        int idx = q * 256 + threadIdx.x;
        int lc = idx >> 5, lk = idx & 31;
        int k = k0 + lk;
        float v = (k < 128) ? Wh[(size_t)(col0 + lc) * 128 + k]
                            : Wi[(size_t)(col0 + lc) * 128 + (k - 128)];
        tile[lc][lk] = v;
    }
    __syncthreads();
    #pragma unroll
    for (int q = 0; q < 4; ++q) {
        int idx = q * 256 + threadIdx.x;
        int lk = idx >> 5, lc = idx & 31;
        WT[(size_t)(k0 + lk) * 512 + col0 + lc] = tile[lc][lk];
    }
}

// ---------------- GEMM 1: x[32000,32] @ {Wl,Wr,Wp} -> xl1, xr1, proj ----------------
__global__ __launch_bounds__(256) void k_gemm_gat1(
    const float* __restrict__ x, const float* __restrict__ Wl, const float* __restrict__ Wr,
    const float* __restrict__ Wp, const float* __restrict__ bp,
    float* __restrict__ xl1, float* __restrict__ xr1, float* __restrict__ proj)
{
    __shared__ float As[32][128];
    __shared__ float Bs[32][132];
    int cbi = blockIdx.x;
    const float* B; float* C; const float* bias = nullptr; int Nc, cof;
    if (cbi < 2)      { B = Wl; C = xl1; Nc = 256; cof = cbi * 128; }
    else if (cbi < 4) { B = Wr; C = xr1; Nc = 256; cof = (cbi - 2) * 128; }
    else              { B = Wp; C = proj; Nc = 128; cof = 0; bias = bp; }
    int tid = threadIdx.x;
    int rowb = blockIdx.y * 128;
    int ra = (tid / 16) * 4, cb = (tid % 16) * 4;
    {
        int ar = tid >> 1, ak = (tid & 1) * 16;
        const float* ap = &x[(size_t)(rowb + ar) * 32 + ak];
        #pragma unroll
        for (int q = 0; q < 4; ++q) {
            float4 v = *(const float4*)(ap + q * 4);
            As[ak + q*4 + 0][ar] = v.x; As[ak + q*4 + 1][ar] = v.y;
            As[ak + q*4 + 2][ar] = v.z; As[ak + q*4 + 3][ar] = v.w;
        }
        int bk = tid >> 3, bc = (tid & 7) * 16;
        const float* bpp = &B[(size_t)bk * Nc + cof + bc];
        #pragma unroll
        for (int q = 0; q < 4; ++q)
            *(float4*)&Bs[bk][bc + q*4] = *(const float4*)(bpp + q*4);
    }
    __syncthreads();
    float acc[8][8] = {};
    #pragma unroll
    for (int kk = 0; kk < 32; ++kk) {
        float4 a0 = *(const float4*)&As[kk][ra];
        float4 a1 = *(const float4*)&As[kk][ra + 64];
        float4 b0 = *(const float4*)&Bs[kk][cb];
        float4 b1 = *(const float4*)&Bs[kk][cb + 64];
        float av[8] = {a0.x,a0.y,a0.z,a0.w,a1.x,a1.y,a1.z,a1.w};
        float bv[8] = {b0.x,b0.y,b0.z,b0.w,b1.x,b1.y,b1.z,b1.w};
        #pragma unroll
        for (int i = 0; i < 8; ++i)
            #pragma unroll
            for (int j = 0; j < 8; ++j)
                acc[i][j] += av[i] * bv[j];
    }
    #pragma unroll
    for (int i = 0; i < 8; ++i) {
        int rloc = ra + (i & 3) + (i >> 2) * 64;
        #pragma unroll
        for (int jg = 0; jg < 2; ++jg)
            #pragma unroll
            for (int j = 0; j < 4; ++j) {
                int col = cb + jg * 64 + j;
                float v = acc[i][jg * 4 + j];
                if (bias) v += bias[col];
                C[(size_t)(rowb + rloc) * Nc + cof + col] = v;
            }
    }
}

// ---------------- GEMM 2: elu(bn(h1)) @ {W2l, W2r} -> xl2, xr2 (bn fused on A-load) ----------------
__global__ __launch_bounds__(256) void k_gemm_gat2(
    const float* __restrict__ h1, const float* __restrict__ Wl, const float* __restrict__ Wr,
    const float* __restrict__ scale1, const float* __restrict__ shift1,
    float* __restrict__ xl2, float* __restrict__ xr2)
{
    __shared__ float As[32][128];
    __shared__ float Bs[32][132];
    const float* B = blockIdx.x ? Wr : Wl;
    float* C = blockIdx.x ? xr2 : xl2;
    int tid = threadIdx.x;
    int rowb = blockIdx.y * 128;
    int ra = (tid / 16) * 4, cb = (tid % 16) * 4;
    int ar = tid >> 1, ak = (tid & 1) * 16;
    int bk = tid >> 3, bc = (tid & 7) * 16;
    int g = (rowb + ar) / NN_;
    const float* scp = scale1 + g * 256;
    const float* shp = shift1 + g * 256;
    float acc[8][8] = {};
    for (int k0 = 0; k0 < 256; k0 += 32) {
        {
            const float* ap = &h1[(size_t)(rowb + ar) * 256 + k0 + ak];
            #pragma unroll
            for (int q = 0; q < 4; ++q) {
                float4 av = *(const float4*)(ap + q * 4);
                float4 sv = *(const float4*)&scp[k0 + ak + q * 4];
                float4 tv = *(const float4*)&shp[k0 + ak + q * 4];
                float v0 = av.x * sv.x + tv.x; v0 = v0 > 0.f ? v0 : expm1f(v0);
                float v1 = av.y * sv.y + tv.y; v1 = v1 > 0.f ? v1 : expm1f(v1);
                float v2 = av.z * sv.z + tv.z; v2 = v2 > 0.f ? v2 : expm1f(v2);
                float v3 = av.w * sv.w + tv.w; v3 = v3 > 0.f ? v3 : expm1f(v3);
                As[ak + q*4 + 0][ar] = v0; As[ak + q*4 + 1][ar] = v1;
                As[ak + q*4 + 2][ar] = v2; As[ak + q*4 + 3][ar] = v3;
            }
            const float* bpp = &B[(size_t)(k0 + bk) * 128 + bc];
            #pragma unroll
            for (int q = 0; q < 4; ++q)
                *(float4*)&Bs[bk][bc + q*4] = *(const float4*)(bpp + q*4);
        }
        __syncthreads();
        #pragma unroll
        for (int kk = 0; kk < 32; ++kk) {
            float4 a0 = *(const float4*)&As[kk][ra];
            float4 a1 = *(const float4*)&As[kk][ra + 64];
            float4 b0 = *(const float4*)&Bs[kk][cb];
            float4 b1 = *(const float4*)&Bs[kk][cb + 64];
            float av[8] = {a0.x,a0.y,a0.z,a0.w,a1.x,a1.y,a1.z,a1.w};
            float bv[8] = {b0.x,b0.y,b0.z,b0.w,b1.x,b1.y,b1.z,b1.w};
            #pragma unroll
            for (int i = 0; i < 8; ++i)
                #pragma unroll
                for (int j = 0; j < 8; ++j)
                    acc[i][j] += av[i] * bv[j];
        }
        __syncthreads();
    }
    #pragma unroll
    for (int i = 0; i < 8; ++i) {
        int rloc = ra + (i & 3) + (i >> 2) * 64;
        #pragma unroll
        for (int jg = 0; jg < 2; ++jg)
            #pragma unroll
            for (int j = 0; j < 4; ++j)
                C[(size_t)(rowb + rloc) * 128 + cb + jg * 64 + j] = acc[i][jg * 4 + j];
    }
}

// ---------------- fused GATv2: logits + per-wave online softmax + aggregate ----------------
template<int NH, int CD>
__global__ void k_gat(const float* __restrict__ xl, const float* __restrict__ xr,
                      const float* __restrict__ att, const int* __restrict__ ei,
                      const int* __restrict__ rowptr, const int* __restrict__ eids,
                      const float* __restrict__ bias, float* __restrict__ out)
{
    const int BD = NH * CD;
    const int NW = BD / 64;
    int g = blockIdx.x / NN_, dst = blockIdx.x % NN_;
    int tid = threadIdx.x, lane = tid & 63, w = tid >> 6;
    int h = tid / CD;
    int rs = rowptr[dst], re = rowptr[dst + 1];
    __shared__ float xrs[BD], atts[BD];
    __shared__ float lgl[64][NH];
    __shared__ int   srcs[64];
    __shared__ float wm[NW][NH], wsum[NW][NH];
    size_t gbase = (size_t)g * NN_;
    xrs[tid]  = xr[(gbase + dst) * BD + tid];
    atts[tid] = att[tid];
    float accM = -1e30f, accS = 0.f, acc = 0.f;
    for (int base = rs; base < re; base += 64) {
        int nl = min(64, re - base);
        __syncthreads();
        if (tid < nl) {
            int eid = eids[base + tid];
            srcs[tid] = eid < E0_ ? ei[eid] : eid - E0_;
        }
        __syncthreads();
        float mw[NH], sw[NH];
        #pragma unroll
        for (int hh = 0; hh < NH; ++hh) { mw[hh] = -1e30f; sw[hh] = 0.f; }
        for (int i = w; i < nl; i += NW) {
            const float* pl = &xl[(gbase + srcs[i]) * BD];
            #pragma unroll
            for (int hh = 0; hh < NH; ++hh) {
                float s = 0.f;
                #pragma unroll
                for (int c = lane; c < CD; c += 64) {
                    float v = pl[hh * CD + c] + xrs[hh * CD + c];
                    v = v > 0.f ? v : 0.2f * v;
                    s = fmaf(v, atts[hh * CD + c], s);
                }
                #pragma unroll
                for (int o = 32; o; o >>= 1) s += __shfl_xor(s, o);
                if (lane == 0) lgl[i][hh] = s;
                float nm = fmaxf(mw[hh], s);
                sw[hh] = sw[hh] * __expf(mw[hh] - nm) + __expf(s - nm);
                mw[hh] = nm;
            }
        }
        if (lane < NH) { wm[w][lane] = mw[lane]; wsum[w][lane] = sw[lane]; }
        __syncthreads();
        // merge per-wave stats (computed redundantly by all threads; uniform)
        float mc[NH], sc[NH];
        #pragma unroll
        for (int hh = 0; hh < NH; ++hh) mc[hh] = -1e30f;
        #pragma unroll
        for (int ww = 0; ww < NW; ++ww)
            #pragma unroll
            for (int hh = 0; hh < NH; ++hh) mc[hh] = fmaxf(mc[hh], wm[ww][hh]);
        #pragma unroll
        for (int hh = 0; hh < NH; ++hh) sc[hh] = 0.f;
        #pragma unroll
        for (int ww = 0; ww < NW; ++ww)
            #pragma unroll
            for (int hh = 0; hh < NH; ++hh) sc[hh] += wsum[ww][hh] * __expf(wm[ww][hh] - mc[hh]);
        if (tid < nl) {
            #pragma unroll
            for (int hh = 0; hh < NH; ++hh) lgl[tid][hh] = __expf(lgl[tid][hh] - mc[hh]);
        }
        __syncthreads();
        // block-level online update (per-thread head h)
        float nM = fmaxf(accM, mc[h]);
        float f_old = __expf(accM - nM), f_new = __expf(mc[h] - nM);
        acc *= f_old;
        accS = accS * f_old + sc[h] * f_new;
        accM = nM;
        int i = 0;
        for (; i + 4 <= nl; i += 4) {
            float e0 = lgl[i][h], e1 = lgl[i+1][h], e2 = lgl[i+2][h], e3 = lgl[i+3][h];
            const float* r0 = &xl[(gbase + srcs[i])   * BD];
            const float* r1 = &xl[(gbase + srcs[i+1]) * BD];
            const float* r2 = &xl[(gbase + srcs[i+2]) * BD];
            const float* r3 = &xl[(gbase + srcs[i+3]) * BD];
            acc += f_new * (e0 * r0[tid] + e1 * r1[tid] + e2 * r2[tid] + e3 * r3[tid]);
        }
        for (; i < nl; ++i)
            acc += f_new * lgl[i][h] * xl[(gbase + srcs[i]) * BD + tid];
    }
    out[(gbase + dst) * BD + tid] = acc / (accS + 1e-16f) + bias[tid];
}

// ---------------- BatchNorm stats -> fused scale/shift ----------------
template<int C>
__global__ __launch_bounds__(C * 4) void k_bnstats(
    const float* __restrict__ h, const float* __restrict__ gamma, const float* __restrict__ beta,
    float* __restrict__ scale, float* __restrict__ shift)
{
    int g = blockIdx.x;
    int c = threadIdx.x % C, q = threadIdx.x / C;
    __shared__ float ps[4][C], pss[4][C];
    float s = 0.f, ss = 0.f;
    for (int n = q * 125; n < (q + 1) * 125; ++n) {
        float v = h[((size_t)g * NN_ + n) * C + c];
        s += v; ss += v * v;
    }
    ps[q][c] = s; pss[q][c] = ss;
    __syncthreads();
    if (q == 0) {
        #pragma unroll
        for (int qq = 1; qq < 4; ++qq) { s += ps[qq][c]; ss += pss[qq][c]; }
        float m = s * (1.f / NN_);
        float var = ss * (1.f / NN_) - m * m;
        float r = rsqrtf(var + 1e-5f);
        float sc = r * gamma[c];
        scale[g * C + c] = sc;
        shift[g * C + c] = beta[c] - m * sc;
    }
}

// ---------------- BN2 apply + ELU + residual add (vectorized) ----------------
__global__ void k_bn_elu_add4(const float* __restrict__ h2, const float* __restrict__ scale2,
                              const float* __restrict__ shift2, const float* __restrict__ proj,
                              float* __restrict__ hres) {
    int i4 = blockIdx.x * blockDim.x + threadIdx.x;
    if (i4 >= G_ * NN_ * HD_ / 4) return;
    int base = i4 * 4;
    int c = base & 127;
    int g = base / (NN_ * HD_);
    float4 hv = *(const float4*)&h2[base];
    float4 sc = *(const float4*)&scale2[g * 128 + c];
    float4 sh = *(const float4*)&shift2[g * 128 + c];
    float4 pv = *(const float4*)&proj[base];
    float v0 = hv.x * sc.x + sh.x; v0 = (v0 > 0.f ? v0 : expm1f(v0)) + pv.x;
    float v1 = hv.y * sc.y + sh.y; v1 = (v1 > 0.f ? v1 : expm1f(v1)) + pv.y;
    float v2 = hv.z * sc.z + sh.z; v2 = (v2 > 0.f ? v2 : expm1f(v2)) + pv.z;
    float v3 = hv.w * sc.w + sh.w; v3 = (v3 > 0.f ? v3 : expm1f(v3)) + pv.w;
    *(float4*)&hres[base] = make_float4(v0, v1, v2, v3);
}

// ---------------- persistent LSTM (both layers, all 16 steps) + FC head ----------------
__device__ __forceinline__ void compute_gates(
    const float (*__restrict__ Ah)[128], const float (*__restrict__ Ax)[128],
    const float* __restrict__ WT, float (*__restrict__ gl)[516], int c2)
{
    float acc0[8], acc1[8];
    #pragma unroll
    for (int r = 0; r < 8; ++r) { acc0[r] = 0.f; acc1[r] = 0.f; }
    #pragma unroll
    for (int half = 0; half < 2; ++half) {
        const float (*__restrict__ A)[128] = half ? Ax : Ah;
        const float* __restrict__ W = WT + (size_t)half * 128 * 512;
        #pragma unroll 2
        for (int k4 = 0; k4 < 128; k4 += 4) {
            float2 w0 = *(const float2*)&W[(size_t)(k4 + 0) * 512 + c2];
            float2 w1 = *(const float2*)&W[(size_t)(k4 + 1) * 512 + c2];
            float2 w2 = *(const float2*)&W[(size_t)(k4 + 2) * 512 + c2];
            float2 w3 = *(const float2*)&W[(size_t)(k4 + 3) * 512 + c2];
            float4 av[8];
            #pragma unroll
            for (int r = 0; r < 8; ++r) av[r] = *(const float4*)&A[r][k4];
            #pragma unroll
            for (int r = 0; r < 8; ++r) {
                acc0[r] += av[r].x * w0.x + av[r].y * w1.x + av[r].z * w2.x + av[r].w * w3.x;
                acc1[r] += av[r].x * w0.y + av[r].y * w1.y + av[r].z * w2.y + av[r].w * w3.y;
            }
        }
    }
    #pragma unroll
    for (int r = 0; r < 8; ++r) { gl[r][c2] = acc0[r]; gl[r][c2 + 1] = acc1[r]; }
}

__device__ __forceinline__ void cell_update(
    const float (*__restrict__ gl)[516], const float* __restrict__ bsum,
    float (*__restrict__ cs)[128], float (*__restrict__ hs)[128], int urow, int u0)
{
    float4 gi = *(const float4*)&gl[urow][u0];
    float4 gf = *(const float4*)&gl[urow][128 + u0];
    float4 gg = *(const float4*)&gl[urow][256 + u0];
    float4 go = *(const float4*)&gl[urow][384 + u0];
    float4 co = *(const float4*)&cs[urow][u0];
    const float* gif = (const float*)&gi; const float* gff = (const float*)&gf;
    const float* ggf = (const float*)&gg; const float* gof = (const float*)&go;
    const float* cof = (const float*)&co;
    float cv[4], hv[4];
    #pragma unroll
    for (int j = 0; j < 4; ++j) {
        float iv = fsig(gif[j] + bsum[0 + j]);
        float fv = fsig(gff[j] + bsum[4 + j]);
        float gv = ftanh(ggf[j] + bsum[8 + j]);
        float ov = fsig(gof[j] + bsum[12 + j]);
        float cn = fv * cof[j] + iv * gv;
        cv[j] = cn;
        hv[j] = ov * ftanh(cn);
    }
    *(float4*)&cs[urow][u0] = make_float4(cv[0], cv[1], cv[2], cv[3]);
    *(float4*)&hs[urow][u0] = make_float4(hv[0], hv[1], hv[2], hv[3]);
}

__global__ __launch_bounds__(256) void k_lstm_all(
    const float* __restrict__ hres, const float* __restrict__ WT0, const float* __restrict__ WT1,
    const float* __restrict__ bih0, const float* __restrict__ bhh0,
    const float* __restrict__ bih1, const float* __restrict__ bhh1,
    const float* __restrict__ fcW1, const float* __restrict__ fcb1,
    const float* __restrict__ fcW2, const float* __restrict__ fcb2,
    float* __restrict__ out)
{
    __shared__ float h1s[8][128], c1s[8][128], h2s[8][128], c2s[8][128];
    __shared__ float xs[8][128];
    __shared__ float gl[8][516];
    int tid = threadIdx.x;
    int r0 = blockIdx.x * 8;
    for (int i = tid; i < 8 * 128; i += 256) {
        int r = i >> 7, k = i & 127;
        h1s[r][k] = 0.f; c1s[r][k] = 0.f; h2s[r][k] = 0.f; c2s[r][k] = 0.f;
    }
    const int c2 = tid * 2;
    const int urow = tid >> 5, u0 = (tid & 31) * 4;
    float bs0[16], bs1[16];
    #pragma unroll
    for (int gt = 0; gt < 4; ++gt)
        #pragma unroll
        for (int j = 0; j < 4; ++j) {
            bs0[gt * 4 + j] = bih0[gt * 128 + u0 + j] + bhh0[gt * 128 + u0 + j];
            bs1[gt * 4 + j] = bih1[gt * 128 + u0 + j] + bhh1[gt * 128 + u0 + j];
        }
    __syncthreads();
    for (int t = 0; t < TT_; ++t) {
        {   // stage x_t for layer 0: lstm row (r0+r) <-> hres row ((r0+r)*16 + t)
            int r = tid >> 5, kq = (tid & 31) * 4;
            *(float4*)&xs[r][kq] = *(const float4*)&hres[(size_t)((r0 + r) * 16 + t) * 128 + kq];
        }
        __syncthreads();
        compute_gates(h1s, xs, WT0, gl, c2);
        __syncthreads();
        cell_update(gl, bs0, c1s, h1s, urow, u0);
        __syncthreads();
        compute_gates(h2s, h1s, WT1, gl, c2);
        __syncthreads();
        cell_update(gl, bs1, c2s, h2s, urow, u0);
        __syncthreads();
    }
    // FC head: relu(h2 @ W1 + b1) @ W2 + b2
    int fr = tid >> 5;
    int j0 = (tid & 31) * 2;
    float s0 = fcb1[j0], s1 = fcb1[j0 + 1];
    for (int k = 0; k < 128; ++k) {
        float hv = h2s[fr][k];
        s0 += hv * fcW1[k * 64 + j0];
        s1 += hv * fcW1[k * 64 + j0 + 1];
    }
    float p = fmaxf(s0, 0.f) * fcW2[j0] + fmaxf(s1, 0.f) * fcW2[j0 + 1];
    #pragma unroll
    for (int o = 16; o; o >>= 1) p += __shfl_xor(p, o);
    if ((tid & 31) == 0) out[r0 + fr] = p + fcb2[0];
}

// ---------------- workspace layout (float offsets) ----------------
static const size_t OFF_XL1  = 0;           // 8,192,000
static const size_t OFF_XR1  = 8192000;     // 8,192,000
static const size_t OFF_H1   = 16384000;    // 8,192,000
static const size_t OFF_XL2  = 24576000;    // 4,096,000
static const size_t OFF_XR2  = 28672000;    // 4,096,000
static const size_t OFF_H2   = 32768000;    // 4,096,000
static const size_t OFF_PRJ  = 36864000;    // 4,096,000
static const size_t OFF_HRES = 40960000;    // 4,096,000
static const size_t OFF_SC1  = 45056000;    // 16384
static const size_t OFF_SH1  = 45072384;    // 16384
static const size_t OFF_SC2  = 45088768;    // 8192
static const size_t OFF_SH2  = 45096960;    // 8192
static const size_t OFF_WT0  = 45105152;    // 131072
static const size_t OFF_WT1  = 45236224;    // 131072
static const size_t OFF_INT  = 45367296;    // int region

extern "C" void kernel_launch(void* const* d_in, const int* in_sizes, int n_in,
                              void* d_out, int out_size, void* d_ws, size_t ws_size,
                              hipStream_t stream) {
    const float* x        = (const float*)d_in[0];
    const int*   ei       = (const int*)  d_in[1];
    const float* W_proj   = (const float*)d_in[2];
    const float* b_proj   = (const float*)d_in[3];
    const float* gat1_Wl  = (const float*)d_in[4];
    const float* gat1_Wr  = (const float*)d_in[5];
    const float* gat1_att = (const float*)d_in[6];
    const float* gat1_b   = (const float*)d_in[7];
    const float* bn1_g    = (const float*)d_in[8];
    const float* bn1_b    = (const float*)d_in[9];
    const float* gat2_Wl  = (const float*)d_in[10];
    const float* gat2_Wr  = (const float*)d_in[11];
    const float* gat2_att = (const float*)d_in[12];
    const float* gat2_b   = (const float*)d_in[13];
    const float* bn2_g    = (const float*)d_in[14];
    const float* bn2_b    = (const float*)d_in[15];
    const float* Wih0     = (const float*)d_in[16];
    const float* Whh0     = (const float*)d_in[17];
    const float* bih0     = (const float*)d_in[18];
    const float* bhh0     = (const float*)d_in[19];
    const float* Wih1     = (const float*)d_in[20];
    const float* Whh1     = (const float*)d_in[21];
    const float* bih1     = (const float*)d_in[22];
    const float* bhh1     = (const float*)d_in[23];
    const float* fc_W1    = (const float*)d_in[24];
    const float* fc_b1    = (const float*)d_in[25];
    const float* fc_W2    = (const float*)d_in[26];
    const float* fc_b2    = (const float*)d_in[27];
    float* out = (float*)d_out;

    float* ws = (float*)d_ws;
    float* xl1  = ws + OFF_XL1;
    float* xr1  = ws + OFF_XR1;
    float* h1   = ws + OFF_H1;
    float* xl2  = ws + OFF_XL2;
    float* xr2  = ws + OFF_XR2;
    float* h2   = ws + OFF_H2;
    float* proj = ws + OFF_PRJ;
    float* hres = ws + OFF_HRES;
    float* sc1  = ws + OFF_SC1;
    float* sh1  = ws + OFF_SH1;
    float* sc2  = ws + OFF_SC2;
    float* sh2  = ws + OFF_SH2;
    float* WT0  = ws + OFF_WT0;
    float* WT1  = ws + OFF_WT1;

    int* ibase  = (int*)(ws + OFF_INT);
    int* deg    = ibase;
    int* rowptr = ibase + 512;
    int* cursor = ibase + 1024;
    int* eids   = ibase + 1536;

    // ---- CSR build + weight transpose ----
    hipMemsetAsync(deg, 0, NN_ * sizeof(int), stream);
    k_deg<<<(EP_ + 255) / 256, 256, 0, stream>>>(ei, deg);
    k_scan<<<1, 1, 0, stream>>>(deg, rowptr, cursor);
    k_fill<<<(EP_ + 255) / 256, 256, 0, stream>>>(ei, cursor, eids);
    k_wt<<<256, 256, 0, stream>>>(Whh0, Wih0, Whh1, Wih1, WT0, WT1);

    // ---- GAT1 ----
    k_gemm_gat1<<<dim3(5, 250), 256, 0, stream>>>(x, gat1_Wl, gat1_Wr, W_proj, b_proj, xl1, xr1, proj);
    k_gat<2, HD_><<<G_ * NN_, 256, 0, stream>>>(xl1, xr1, gat1_att, ei, rowptr, eids, gat1_b, h1);
    k_bnstats<C1_><<<G_, C1_ * 4, 0, stream>>>(h1, bn1_g, bn1_b, sc1, sh1);

    // ---- GAT2 (bn1+elu fused into A-load) ----
    k_gemm_gat2<<<dim3(2, 250), 256, 0, stream>>>(h1, gat2_Wl, gat2_Wr, sc1, sh1, xl2, xr2);
    k_gat<1, HD_><<<G_ * NN_, 128, 0, stream>>>(xl2, xr2, gat2_att, ei, rowptr, eids, gat2_b, h2);
    k_bnstats<HD_><<<G_, HD_ * 4, 0, stream>>>(h2, bn2_g, bn2_b, sc2, sh2);

    // ---- BN2 + ELU + residual ----
    k_bn_elu_add4<<<(G_ * NN_ * HD_ / 4 + 255) / 256, 256, 0, stream>>>(h2, sc2, sh2, proj, hres);

    // ---- persistent LSTM (both layers, all steps) + FC head ----
    k_lstm_all<<<NR_ / 8, 256, 0, stream>>>(hres, WT0, WT1, bih0, bhh0, bih1, bhh1,
                                            fc_W1, fc_b1, fc_W2, fc_b2, out);
}

// Round 4
// 994.758 us; speedup vs baseline: 1.0659x; 1.0659x over previous
//
#include <hip/hip_runtime.h>
#include <hip/hip_bf16.h>
#include <math.h>

#define G_   64      // B*T graphs
#define NN_  500     // nodes
#define FIN_ 32
#define HD_  128
#define C1_  256     // HEADS*HD
#define E0_  8000
#define EP_  8500    // E0 + self loops
#define TT_  16
#define NR_  2000    // B*N lstm rows

__device__ __forceinline__ float fsig(float x)  { return 1.f / (1.f + __expf(-x)); }
__device__ __forceinline__ float ftanh(float x) {
    float e = __expf(fminf(fmaxf(2.f * x, -30.f), 30.f));
    return (e - 1.f) / (e + 1.f);
}

// ---------------- CSR build (by dst) ----------------
__global__ void k_deg(const int* __restrict__ ei, int* __restrict__ deg) {
    int e = blockIdx.x * blockDim.x + threadIdx.x;
    if (e >= EP_) return;
    int dst = e < E0_ ? ei[E0_ + e] : e - E0_;
    atomicAdd(&deg[dst], 1);
}
__global__ void k_scan(const int* __restrict__ deg, int* __restrict__ rowptr, int* __restrict__ cursor) {
    if (threadIdx.x == 0 && blockIdx.x == 0) {
        int acc = 0;
        for (int i = 0; i < NN_; ++i) { rowptr[i] = acc; cursor[i] = acc; acc += deg[i]; }
        rowptr[NN_] = acc;
    }
}
__global__ void k_fill(const int* __restrict__ ei, int* __restrict__ cursor, int* __restrict__ eids) {
    int e = blockIdx.x * blockDim.x + threadIdx.x;
    if (e >= EP_) return;
    int dst = e < E0_ ? ei[E0_ + e] : e - E0_;
    int pos = atomicAdd(&cursor[dst], 1);
    eids[pos] = e;
}

// ---------------- weight transpose for LSTM: WT[k][col], k = [Whh | Wih] ----------------
__global__ void k_wt(const float* __restrict__ Whh0, const float* __restrict__ Wih0,
                     const float* __restrict__ Whh1, const float* __restrict__ Wih1,
                     float* __restrict__ WT0, float* __restrict__ WT1) {
    __shared__ float tile[32][33];
    int b = blockIdx.x;
    int layer = b >> 7; int rem = b & 127;
    int kb = rem >> 4, cbk = rem & 15;
    const float* Wh = layer ? Whh1 : Whh0;
    const float* Wi = layer ? Wih1 : Wih0;
    float* WT = layer ? WT1 : WT0;
    int k0 = kb * 32, col0 = cbk * 32;
    #pragma unroll
    for (int q = 0; q < 4; ++q) {
        int idx = q * 256 + threadIdx.x;
        int lc = idx >> 5, lk = idx & 31;
        int k = k0 + lk;
        float v = (k < 128) ? Wh[(size_t)(col0 + lc) * 128 + k]
                            : Wi[(size_t)(col0 + lc) * 128 + (k - 128)];
        tile[lc][lk] = v;
    }
    __syncthreads();
    #pragma unroll
    for (int q = 0; q < 4; ++q) {
        int idx = q * 256 + threadIdx.x;
        int lk = idx >> 5, lc = idx & 31;
        WT[(size_t)(k0 + lk) * 512 + col0 + lc] = tile[lc][lk];
    }
}

// ---------------- GEMM 1: x[32000,32] @ {Wl,Wr,Wp} -> xl1, xr1, proj ----------------
__global__ __launch_bounds__(256) void k_gemm_gat1(
    const float* __restrict__ x, const float* __restrict__ Wl, const float* __restrict__ Wr,
    const float* __restrict__ Wp, const float* __restrict__ bp,
    float* __restrict__ xl1, float* __restrict__ xr1, float* __restrict__ proj)
{
    __shared__ float As[32][128];
    __shared__ float Bs[32][132];
    int cbi = blockIdx.x;
    const float* B; float* C; const float* bias = nullptr; int Nc, cof;
    if (cbi < 2)      { B = Wl; C = xl1; Nc = 256; cof = cbi * 128; }
    else if (cbi < 4) { B = Wr; C = xr1; Nc = 256; cof = (cbi - 2) * 128; }
    else              { B = Wp; C = proj; Nc = 128; cof = 0; bias = bp; }
    int tid = threadIdx.x;
    int rowb = blockIdx.y * 128;
    int ra = (tid / 16) * 4, cb = (tid % 16) * 4;
    {
        int ar = tid >> 1, ak = (tid & 1) * 16;
        const float* ap = &x[(size_t)(rowb + ar) * 32 + ak];
        #pragma unroll
        for (int q = 0; q < 4; ++q) {
            float4 v = *(const float4*)(ap + q * 4);
            As[ak + q*4 + 0][ar] = v.x; As[ak + q*4 + 1][ar] = v.y;
            As[ak + q*4 + 2][ar] = v.z; As[ak + q*4 + 3][ar] = v.w;
        }
        int bk = tid >> 3, bc = (tid & 7) * 16;
        const float* bpp = &B[(size_t)bk * Nc + cof + bc];
        #pragma unroll
        for (int q = 0; q < 4; ++q)
            *(float4*)&Bs[bk][bc + q*4] = *(const float4*)(bpp + q*4);
    }
    __syncthreads();
    float acc[8][8] = {};
    #pragma unroll
    for (int kk = 0; kk < 32; ++kk) {
        float4 a0 = *(const float4*)&As[kk][ra];
        float4 a1 = *(const float4*)&As[kk][ra + 64];
        float4 b0 = *(const float4*)&Bs[kk][cb];
        float4 b1 = *(const float4*)&Bs[kk][cb + 64];
        float av[8] = {a0.x,a0.y,a0.z,a0.w,a1.x,a1.y,a1.z,a1.w};
        float bv[8] = {b0.x,b0.y,b0.z,b0.w,b1.x,b1.y,b1.z,b1.w};
        #pragma unroll
        for (int i = 0; i < 8; ++i)
            #pragma unroll
            for (int j = 0; j < 8; ++j)
                acc[i][j] += av[i] * bv[j];
    }
    #pragma unroll
    for (int i = 0; i < 8; ++i) {
        int rloc = ra + (i & 3) + (i >> 2) * 64;
        #pragma unroll
        for (int jg = 0; jg < 2; ++jg)
            #pragma unroll
            for (int j = 0; j < 4; ++j) {
                int col = cb + jg * 64 + j;
                float v = acc[i][jg * 4 + j];
                if (bias) v += bias[col];
                C[(size_t)(rowb + rloc) * Nc + cof + col] = v;
            }
    }
}

// ---------------- GEMM 2: elu(bn(h1)) @ {W2l, W2r} -> xl2, xr2 (bn fused on A-load) ----------------
__global__ __launch_bounds__(256) void k_gemm_gat2(
    const float* __restrict__ h1, const float* __restrict__ Wl, const float* __restrict__ Wr,
    const float* __restrict__ scale1, const float* __restrict__ shift1,
    float* __restrict__ xl2, float* __restrict__ xr2)
{
    __shared__ float As[32][128];
    __shared__ float Bs[32][132];
    const float* B = blockIdx.x ? Wr : Wl;
    float* C = blockIdx.x ? xr2 : xl2;
    int tid = threadIdx.x;
    int rowb = blockIdx.y * 128;
    int ra = (tid / 16) * 4, cb = (tid % 16) * 4;
    int ar = tid >> 1, ak = (tid & 1) * 16;
    int bk = tid >> 3, bc = (tid & 7) * 16;
    int g = (rowb + ar) / NN_;
    const float* scp = scale1 + g * 256;
    const float* shp = shift1 + g * 256;
    float acc[8][8] = {};
    for (int k0 = 0; k0 < 256; k0 += 32) {
        {
            const float* ap = &h1[(size_t)(rowb + ar) * 256 + k0 + ak];
            #pragma unroll
            for (int q = 0; q < 4; ++q) {
                float4 av = *(const float4*)(ap + q * 4);
                float4 sv = *(const float4*)&scp[k0 + ak + q * 4];
                float4 tv = *(const float4*)&shp[k0 + ak + q * 4];
                float v0 = av.x * sv.x + tv.x; v0 = v0 > 0.f ? v0 : expm1f(v0);
                float v1 = av.y * sv.y + tv.y; v1 = v1 > 0.f ? v1 : expm1f(v1);
                float v2 = av.z * sv.z + tv.z; v2 = v2 > 0.f ? v2 : expm1f(v2);
                float v3 = av.w * sv.w + tv.w; v3 = v3 > 0.f ? v3 : expm1f(v3);
                As[ak + q*4 + 0][ar] = v0; As[ak + q*4 + 1][ar] = v1;
                As[ak + q*4 + 2][ar] = v2; As[ak + q*4 + 3][ar] = v3;
            }
            const float* bpp = &B[(size_t)(k0 + bk) * 128 + bc];
            #pragma unroll
            for (int q = 0; q < 4; ++q)
                *(float4*)&Bs[bk][bc + q*4] = *(const float4*)(bpp + q*4);
        }
        __syncthreads();
        #pragma unroll
        for (int kk = 0; kk < 32; ++kk) {
            float4 a0 = *(const float4*)&As[kk][ra];
            float4 a1 = *(const float4*)&As[kk][ra + 64];
            float4 b0 = *(const float4*)&Bs[kk][cb];
            float4 b1 = *(const float4*)&Bs[kk][cb + 64];
            float av[8] = {a0.x,a0.y,a0.z,a0.w,a1.x,a1.y,a1.z,a1.w};
            float bv[8] = {b0.x,b0.y,b0.z,b0.w,b1.x,b1.y,b1.z,b1.w};
            #pragma unroll
            for (int i = 0; i < 8; ++i)
                #pragma unroll
                for (int j = 0; j < 8; ++j)
                    acc[i][j] += av[i] * bv[j];
        }
        __syncthreads();
    }
    #pragma unroll
    for (int i = 0; i < 8; ++i) {
        int rloc = ra + (i & 3) + (i >> 2) * 64;
        #pragma unroll
        for (int jg = 0; jg < 2; ++jg)
            #pragma unroll
            for (int j = 0; j < 4; ++j)
                C[(size_t)(rowb + rloc) * 128 + cb + jg * 64 + j] = acc[i][jg * 4 + j];
    }
}

// ---------------- fused GATv2: logits + per-wave online softmax + aggregate ----------------
template<int NH, int CD>
__global__ void k_gat(const float* __restrict__ xl, const float* __restrict__ xr,
                      const float* __restrict__ att, const int* __restrict__ ei,
                      const int* __restrict__ rowptr, const int* __restrict__ eids,
                      const float* __restrict__ bias, float* __restrict__ out)
{
    const int BD = NH * CD;
    const int NW = BD / 64;
    int g = blockIdx.x / NN_, dst = blockIdx.x % NN_;
    int tid = threadIdx.x, lane = tid & 63, w = tid >> 6;
    int h = tid / CD;
    int rs = rowptr[dst], re = rowptr[dst + 1];
    __shared__ float xrs[BD], atts[BD];
    __shared__ float lgl[64][NH];
    __shared__ int   srcs[64];
    __shared__ float wm[NW][NH], wsum[NW][NH];
    size_t gbase = (size_t)g * NN_;
    xrs[tid]  = xr[(gbase + dst) * BD + tid];
    atts[tid] = att[tid];
    float accM = -1e30f, accS = 0.f, acc = 0.f;
    for (int base = rs; base < re; base += 64) {
        int nl = min(64, re - base);
        __syncthreads();
        if (tid < nl) {
            int eid = eids[base + tid];
            srcs[tid] = eid < E0_ ? ei[eid] : eid - E0_;
        }
        __syncthreads();
        float mw[NH], sw[NH];
        #pragma unroll
        for (int hh = 0; hh < NH; ++hh) { mw[hh] = -1e30f; sw[hh] = 0.f; }
        for (int i = w; i < nl; i += NW) {
            const float* pl = &xl[(gbase + srcs[i]) * BD];
            #pragma unroll
            for (int hh = 0; hh < NH; ++hh) {
                float s = 0.f;
                #pragma unroll
                for (int c = lane; c < CD; c += 64) {
                    float v = pl[hh * CD + c] + xrs[hh * CD + c];
                    v = v > 0.f ? v : 0.2f * v;
                    s = fmaf(v, atts[hh * CD + c], s);
                }
                #pragma unroll
                for (int o = 32; o; o >>= 1) s += __shfl_xor(s, o);
                if (lane == 0) lgl[i][hh] = s;
                float nm = fmaxf(mw[hh], s);
                sw[hh] = sw[hh] * __expf(mw[hh] - nm) + __expf(s - nm);
                mw[hh] = nm;
            }
        }
        if (lane < NH) { wm[w][lane] = mw[lane]; wsum[w][lane] = sw[lane]; }
        __syncthreads();
        // merge per-wave stats (computed redundantly by all threads; uniform)
        float mc[NH], sc[NH];
        #pragma unroll
        for (int hh = 0; hh < NH; ++hh) mc[hh] = -1e30f;
        #pragma unroll
        for (int ww = 0; ww < NW; ++ww)
            #pragma unroll
            for (int hh = 0; hh < NH; ++hh) mc[hh] = fmaxf(mc[hh], wm[ww][hh]);
        #pragma unroll
        for (int hh = 0; hh < NH; ++hh) sc[hh] = 0.f;
        #pragma unroll
        for (int ww = 0; ww < NW; ++ww)
            #pragma unroll
            for (int hh = 0; hh < NH; ++hh) sc[hh] += wsum[ww][hh] * __expf(wm[ww][hh] - mc[hh]);
        if (tid < nl) {
            #pragma unroll
            for (int hh = 0; hh < NH; ++hh) lgl[tid][hh] = __expf(lgl[tid][hh] - mc[hh]);
        }
        __syncthreads();
        // block-level online update (per-thread head h)
        float nM = fmaxf(accM, mc[h]);
        float f_old = __expf(accM - nM), f_new = __expf(mc[h] - nM);
        acc *= f_old;
        accS = accS * f_old + sc[h] * f_new;
        accM = nM;
        int i = 0;
        for (; i + 4 <= nl; i += 4) {
            float e0 = lgl[i][h], e1 = lgl[i+1][h], e2 = lgl[i+2][h], e3 = lgl[i+3][h];
            const float* r0 = &xl[(gbase + srcs[i])   * BD];
            const float* r1 = &xl[(gbase + srcs[i+1]) * BD];
            const float* r2 = &xl[(gbase + srcs[i+2]) * BD];
            const float* r3 = &xl[(gbase + srcs[i+3]) * BD];
            acc += f_new * (e0 * r0[tid] + e1 * r1[tid] + e2 * r2[tid] + e3 * r3[tid]);
        }
        for (; i < nl; ++i)
            acc += f_new * lgl[i][h] * xl[(gbase + srcs[i]) * BD + tid];
    }
    out[(gbase + dst) * BD + tid] = acc / (accS + 1e-16f) + bias[tid];
}

// ---------------- BatchNorm stats -> fused scale/shift ----------------
template<int C>
__global__ __launch_bounds__(C * 4) void k_bnstats(
    const float* __restrict__ h, const float* __restrict__ gamma, const float* __restrict__ beta,
    float* __restrict__ scale, float* __restrict__ shift)
{
    int g = blockIdx.x;
    int c = threadIdx.x % C, q = threadIdx.x / C;
    __shared__ float ps[4][C], pss[4][C];
    float s = 0.f, ss = 0.f;
    for (int n = q * 125; n < (q + 1) * 125; ++n) {
        float v = h[((size_t)g * NN_ + n) * C + c];
        s += v; ss += v * v;
    }
    ps[q][c] = s; pss[q][c] = ss;
    __syncthreads();
    if (q == 0) {
        #pragma unroll
        for (int qq = 1; qq < 4; ++qq) { s += ps[qq][c]; ss += pss[qq][c]; }
        float m = s * (1.f / NN_);
        float var = ss * (1.f / NN_) - m * m;
        float r = rsqrtf(var + 1e-5f);
        float sc = r * gamma[c];
        scale[g * C + c] = sc;
        shift[g * C + c] = beta[c] - m * sc;
    }
}

// ---------------- BN2 apply + ELU + residual add (vectorized) ----------------
__global__ void k_bn_elu_add4(const float* __restrict__ h2, const float* __restrict__ scale2,
                              const float* __restrict__ shift2, const float* __restrict__ proj,
                              float* __restrict__ hres) {
    int i4 = blockIdx.x * blockDim.x + threadIdx.x;
    if (i4 >= G_ * NN_ * HD_ / 4) return;
    int base = i4 * 4;
    int c = base & 127;
    int g = base / (NN_ * HD_);
    float4 hv = *(const float4*)&h2[base];
    float4 sc = *(const float4*)&scale2[g * 128 + c];
    float4 sh = *(const float4*)&shift2[g * 128 + c];
    float4 pv = *(const float4*)&proj[base];
    float v0 = hv.x * sc.x + sh.x; v0 = (v0 > 0.f ? v0 : expm1f(v0)) + pv.x;
    float v1 = hv.y * sc.y + sh.y; v1 = (v1 > 0.f ? v1 : expm1f(v1)) + pv.y;
    float v2 = hv.z * sc.z + sh.z; v2 = (v2 > 0.f ? v2 : expm1f(v2)) + pv.z;
    float v3 = hv.w * sc.w + sh.w; v3 = (v3 > 0.f ? v3 : expm1f(v3)) + pv.w;
    *(float4*)&hres[base] = make_float4(v0, v1, v2, v3);
}

// ---------------- persistent LSTM (both layers, all 16 steps) + FC head ----------------
// 250 blocks x 512 threads (8 waves -> 2 waves/SIMD). Thread = 4 rows x 2 gate-cols,
// weight loads software-pipelined one k8-iteration ahead.
__device__ __forceinline__ void compute_gates512(
    const float* __restrict__ Ah, const float* __restrict__ Ax,
    const float* __restrict__ WT, float* __restrict__ gl, int rh, int c2)
{
    float acc0[4] = {}, acc1[4] = {};
    const float* arow = (rh ? Ah + 4 * 128 : Ah);
    const float* xrow = (rh ? Ax + 4 * 128 : Ax);
    float2 wc[8], wn[8];
    {
        const float* wp = WT + c2;
        #pragma unroll
        for (int q = 0; q < 8; ++q) wc[q] = *(const float2*)(wp + q * 512);
    }
    #pragma unroll 4
    for (int it = 0; it < 32; ++it) {
        // prefetch next iteration's weights
        if (it < 31) {
            const float* wp = WT + (size_t)((it + 1) * 8) * 512 + c2;
            #pragma unroll
            for (int q = 0; q < 8; ++q) wn[q] = *(const float2*)(wp + q * 512);
        }
        const float* src = (it < 16) ? arow : xrow;
        int kk = (it & 15) * 8;
        #pragma unroll
        for (int r = 0; r < 4; ++r) {
            float4 a0 = *(const float4*)&src[r * 128 + kk];
            float4 a1 = *(const float4*)&src[r * 128 + kk + 4];
            acc0[r] += a0.x * wc[0].x + a0.y * wc[1].x + a0.z * wc[2].x + a0.w * wc[3].x
                     + a1.x * wc[4].x + a1.y * wc[5].x + a1.z * wc[6].x + a1.w * wc[7].x;
            acc1[r] += a0.x * wc[0].y + a0.y * wc[1].y + a0.z * wc[2].y + a0.w * wc[3].y
                     + a1.x * wc[4].y + a1.y * wc[5].y + a1.z * wc[6].y + a1.w * wc[7].y;
        }
        #pragma unroll
        for (int q = 0; q < 8; ++q) wc[q] = wn[q];
    }
    #pragma unroll
    for (int r = 0; r < 4; ++r) {
        gl[(rh * 4 + r) * 520 + c2]     = acc0[r];
        gl[(rh * 4 + r) * 520 + c2 + 1] = acc1[r];
    }
}

__device__ __forceinline__ void cell_update512(
    const float* __restrict__ gl, const float* __restrict__ bs,
    float (*__restrict__ cs)[128], float (*__restrict__ hs)[128], int ur, int uc)
{
    #pragma unroll
    for (int half = 0; half < 2; ++half) {
        int c = uc + half * 64;
        const float* gr = gl + ur * 520;
        float gi = gr[c]       + bs[half * 4 + 0];
        float gf = gr[128 + c] + bs[half * 4 + 1];
        float gg = gr[256 + c] + bs[half * 4 + 2];
        float go = gr[384 + c] + bs[half * 4 + 3];
        float iv = fsig(gi), fv = fsig(gf), gv = ftanh(gg), ov = fsig(go);
        float cn = fv * cs[ur][c] + iv * gv;
        cs[ur][c] = cn;
        hs[ur][c] = ov * ftanh(cn);
    }
}

__global__ __launch_bounds__(512) void k_lstm_all(
    const float* __restrict__ hres, const float* __restrict__ WT0, const float* __restrict__ WT1,
    const float* __restrict__ bih0, const float* __restrict__ bhh0,
    const float* __restrict__ bih1, const float* __restrict__ bhh1,
    const float* __restrict__ fcW1, const float* __restrict__ fcb1,
    const float* __restrict__ fcW2, const float* __restrict__ fcb2,
    float* __restrict__ out)
{
    __shared__ float h1s[8][128], c1s[8][128], h2s[8][128], c2s[8][128];
    __shared__ float xs[8][128];
    __shared__ float gl[8 * 520];
    int tid = threadIdx.x;                 // 0..511
    int r0 = blockIdx.x * 8;
    int rh = tid >> 8;                     // 0/1: rows rh*4 .. rh*4+3
    int c2 = (tid & 255) * 2;              // gate cols c2, c2+1
    int ur = tid >> 6, uc = tid & 63;      // cell-update mapping (2 elems/thread)

    for (int i = tid; i < 8 * 128; i += 512) {
        int r = i >> 7, k = i & 127;
        h1s[r][k] = 0.f; c1s[r][k] = 0.f; h2s[r][k] = 0.f; c2s[r][k] = 0.f;
    }
    float bs0[8], bs1[8];
    #pragma unroll
    for (int half = 0; half < 2; ++half)
        #pragma unroll
        for (int gt = 0; gt < 4; ++gt) {
            int c = uc + half * 64;
            bs0[half * 4 + gt] = bih0[gt * 128 + c] + bhh0[gt * 128 + c];
            bs1[half * 4 + gt] = bih1[gt * 128 + c] + bhh1[gt * 128 + c];
        }
    {   // stage x_0
        int r = tid >> 6, kq = (tid & 63) * 2;
        *(float2*)&xs[r][kq] = *(const float2*)&hres[(size_t)((r0 + r) * 16 + 0) * 128 + kq];
    }
    __syncthreads();
    for (int t = 0; t < TT_; ++t) {
        compute_gates512(&h1s[0][0], &xs[0][0], WT0, gl, rh, c2);
        __syncthreads();
        cell_update512(gl, bs0, c1s, h1s, ur, uc);
        __syncthreads();
        compute_gates512(&h2s[0][0], &h1s[0][0], WT1, gl, rh, c2);
        __syncthreads();
        cell_update512(gl, bs1, c2s, h2s, ur, uc);
        if (t < TT_ - 1) {   // stage x_{t+1} (read by gates1 after the sync)
            int r = tid >> 6, kq = (tid & 63) * 2;
            *(float2*)&xs[r][kq] = *(const float2*)&hres[(size_t)((r0 + r) * 16 + t + 1) * 128 + kq];
        }
        __syncthreads();
    }
    // FC head: relu(h2 @ W1 + b1) @ W2 + b2 ; one wave per row
    int fr = tid >> 6;       // 0..7 (uniform per wave)
    int j = tid & 63;
    float s = fcb1[j];
    #pragma unroll 8
    for (int k = 0; k < 128; ++k) s += h2s[fr][k] * fcW1[k * 64 + j];
    float p = fmaxf(s, 0.f) * fcW2[j];
    #pragma unroll
    for (int o = 32; o; o >>= 1) p += __shfl_xor(p, o);
    if (j == 0) out[r0 + fr] = p + fcb2[0];
}

// ---------------- workspace layout (float offsets) ----------------
static const size_t OFF_XL1  = 0;           // 8,192,000
static const size_t OFF_XR1  = 8192000;     // 8,192,000
static const size_t OFF_H1   = 16384000;    // 8,192,000
static const size_t OFF_XL2  = 24576000;    // 4,096,000
static const size_t OFF_XR2  = 28672000;    // 4,096,000
static const size_t OFF_H2   = 32768000;    // 4,096,000
static const size_t OFF_PRJ  = 36864000;    // 4,096,000
static const size_t OFF_HRES = 40960000;    // 4,096,000
static const size_t OFF_SC1  = 45056000;    // 16384
static const size_t OFF_SH1  = 45072384;    // 16384
static const size_t OFF_SC2  = 45088768;    // 8192
static const size_t OFF_SH2  = 45096960;    // 8192
static const size_t OFF_WT0  = 45105152;    // 131072
static const size_t OFF_WT1  = 45236224;    // 131072
static const size_t OFF_INT  = 45367296;    // int region

extern "C" void kernel_launch(void* const* d_in, const int* in_sizes, int n_in,
                              void* d_out, int out_size, void* d_ws, size_t ws_size,
                              hipStream_t stream) {
    const float* x        = (const float*)d_in[0];
    const int*   ei       = (const int*)  d_in[1];
    const float* W_proj   = (const float*)d_in[2];
    const float* b_proj   = (const float*)d_in[3];
    const float* gat1_Wl  = (const float*)d_in[4];
    const float* gat1_Wr  = (const float*)d_in[5];
    const float* gat1_att = (const float*)d_in[6];
    const float* gat1_b   = (const float*)d_in[7];
    const float* bn1_g    = (const float*)d_in[8];
    const float* bn1_b    = (const float*)d_in[9];
    const float* gat2_Wl  = (const float*)d_in[10];
    const float* gat2_Wr  = (const float*)d_in[11];
    const float* gat2_att = (const float*)d_in[12];
    const float* gat2_b   = (const float*)d_in[13];
    const float* bn2_g    = (const float*)d_in[14];
    const float* bn2_b    = (const float*)d_in[15];
    const float* Wih0     = (const float*)d_in[16];
    const float* Whh0     = (const float*)d_in[17];
    const float* bih0     = (const float*)d_in[18];
    const float* bhh0     = (const float*)d_in[19];
    const float* Wih1     = (const float*)d_in[20];
    const float* Whh1     = (const float*)d_in[21];
    const float* bih1     = (const float*)d_in[22];
    const float* bhh1     = (const float*)d_in[23];
    const float* fc_W1    = (const float*)d_in[24];
    const float* fc_b1    = (const float*)d_in[25];
    const float* fc_W2    = (const float*)d_in[26];
    const float* fc_b2    = (const float*)d_in[27];
    float* out = (float*)d_out;

    float* ws = (float*)d_ws;
    float* xl1  = ws + OFF_XL1;
    float* xr1  = ws + OFF_XR1;
    float* h1   = ws + OFF_H1;
    float* xl2  = ws + OFF_XL2;
    float* xr2  = ws + OFF_XR2;
    float* h2   = ws + OFF_H2;
    float* proj = ws + OFF_PRJ;
    float* hres = ws + OFF_HRES;
    float* sc1  = ws + OFF_SC1;
    float* sh1  = ws + OFF_SH1;
    float* sc2  = ws + OFF_SC2;
    float* sh2  = ws + OFF_SH2;
    float* WT0  = ws + OFF_WT0;
    float* WT1  = ws + OFF_WT1;

    int* ibase  = (int*)(ws + OFF_INT);
    int* deg    = ibase;
    int* rowptr = ibase + 512;
    int* cursor = ibase + 1024;
    int* eids   = ibase + 1536;

    // ---- CSR build + weight transpose ----
    hipMemsetAsync(deg, 0, NN_ * sizeof(int), stream);
    k_deg<<<(EP_ + 255) / 256, 256, 0, stream>>>(ei, deg);
    k_scan<<<1, 1, 0, stream>>>(deg, rowptr, cursor);
    k_fill<<<(EP_ + 255) / 256, 256, 0, stream>>>(ei, cursor, eids);
    k_wt<<<256, 256, 0, stream>>>(Whh0, Wih0, Whh1, Wih1, WT0, WT1);

    // ---- GAT1 ----
    k_gemm_gat1<<<dim3(5, 250), 256, 0, stream>>>(x, gat1_Wl, gat1_Wr, W_proj, b_proj, xl1, xr1, proj);
    k_gat<2, HD_><<<G_ * NN_, 256, 0, stream>>>(xl1, xr1, gat1_att, ei, rowptr, eids, gat1_b, h1);
    k_bnstats<C1_><<<G_, C1_ * 4, 0, stream>>>(h1, bn1_g, bn1_b, sc1, sh1);

    // ---- GAT2 (bn1+elu fused into A-load) ----
    k_gemm_gat2<<<dim3(2, 250), 256, 0, stream>>>(h1, gat2_Wl, gat2_Wr, sc1, sh1, xl2, xr2);
    k_gat<1, HD_><<<G_ * NN_, 128, 0, stream>>>(xl2, xr2, gat2_att, ei, rowptr, eids, gat2_b, h2);
    k_bnstats<HD_><<<G_, HD_ * 4, 0, stream>>>(h2, bn2_g, bn2_b, sc2, sh2);

    // ---- BN2 + ELU + residual ----
    k_bn_elu_add4<<<(G_ * NN_ * HD_ / 4 + 255) / 256, 256, 0, stream>>>(h2, sc2, sh2, proj, hres);

    // ---- persistent LSTM (both layers, all steps) + FC head ----
    k_lstm_all<<<NR_ / 8, 512, 0, stream>>>(hres, WT0, WT1, bih0, bhh0, bih1, bhh1,
                                            fc_W1, fc_b1, fc_W2, fc_b2, out);
}

// Round 5
// 681.359 us; speedup vs baseline: 1.5562x; 1.4600x over previous
//
#include <hip/hip_runtime.h>
#include <hip/hip_bf16.h>
#include <math.h>

#define G_   64      // B*T graphs
#define NN_  500     // nodes
#define FIN_ 32
#define HD_  128
#define C1_  256     // HEADS*HD
#define E0_  8000
#define EP_  8500    // E0 + self loops
#define TT_  16
#define NR_  2000    // B*N lstm rows

typedef __attribute__((ext_vector_type(8))) short bf16x8;
typedef __attribute__((ext_vector_type(4))) float f32x4;

__device__ __forceinline__ float fsig(float x)  { return 1.f / (1.f + __expf(-x)); }
__device__ __forceinline__ float ftanh(float x) {
    float e = __expf(fminf(fmaxf(2.f * x, -30.f), 30.f));
    return (e - 1.f) / (e + 1.f);
}
__device__ __forceinline__ unsigned short f2bf(float f) {
    unsigned int u = __float_as_uint(f);
    return (unsigned short)((u + 0x7FFFu + ((u >> 16) & 1u)) >> 16);
}
__device__ __forceinline__ float bf2f(unsigned short h) {
    return __uint_as_float(((unsigned int)h) << 16);
}

// ---------------- CSR build (by dst) ----------------
__global__ void k_deg(const int* __restrict__ ei, int* __restrict__ deg) {
    int e = blockIdx.x * blockDim.x + threadIdx.x;
    if (e >= EP_) return;
    int dst = e < E0_ ? ei[E0_ + e] : e - E0_;
    atomicAdd(&deg[dst], 1);
}
__global__ void k_scan(const int* __restrict__ deg, int* __restrict__ rowptr, int* __restrict__ cursor) {
    if (threadIdx.x == 0 && blockIdx.x == 0) {
        int acc = 0;
        for (int i = 0; i < NN_; ++i) { rowptr[i] = acc; cursor[i] = acc; acc += deg[i]; }
        rowptr[NN_] = acc;
    }
}
__global__ void k_fill(const int* __restrict__ ei, int* __restrict__ cursor, int* __restrict__ eids) {
    int e = blockIdx.x * blockDim.x + threadIdx.x;
    if (e >= EP_) return;
    int dst = e < E0_ ? ei[E0_ + e] : e - E0_;
    int pos = atomicAdd(&cursor[dst], 1);
    eids[pos] = e;
}

// ---------------- LSTM weight prepack: split-bf16, MFMA B-fragment layout ----------------
// WB layout per layer: [hi: 131072][lo: 131072] ushort.
// index(k, col) = ((k>>3)*512 + col)*8 + (k&7), k = [Whh k<128 | Wih k-128], col in [0,512).
__global__ void k_wt(const float* __restrict__ Whh0, const float* __restrict__ Wih0,
                     const float* __restrict__ Whh1, const float* __restrict__ Wih1,
                     unsigned short* __restrict__ WB0, unsigned short* __restrict__ WB1) {
    int layer = blockIdx.y;
    int n = blockIdx.x * 256 + threadIdx.x;   // 0..131071
    const float* Wh = layer ? Whh1 : Whh0;
    const float* Wi = layer ? Wih1 : Wih0;
    unsigned short* WB = layer ? WB1 : WB0;
    int j = n & 7, col = (n >> 3) & 511, kb8 = n >> 12;
    int k = kb8 * 8 + j;
    float w = (k < 128) ? Wh[(size_t)col * 128 + k] : Wi[(size_t)col * 128 + (k - 128)];
    unsigned short h = f2bf(w);
    WB[n] = h;
    WB[131072 + n] = f2bf(w - bf2f(h));
}

// ---------------- GEMM 1: x[32000,32] @ {Wl,Wr,Wp} -> xl1, xr1, proj ----------------
__global__ __launch_bounds__(256) void k_gemm_gat1(
    const float* __restrict__ x, const float* __restrict__ Wl, const float* __restrict__ Wr,
    const float* __restrict__ Wp, const float* __restrict__ bp,
    float* __restrict__ xl1, float* __restrict__ xr1, float* __restrict__ proj)
{
    __shared__ float As[32][128];
    __shared__ float Bs[32][132];
    int cbi = blockIdx.x;
    const float* B; float* C; const float* bias = nullptr; int Nc, cof;
    if (cbi < 2)      { B = Wl; C = xl1; Nc = 256; cof = cbi * 128; }
    else if (cbi < 4) { B = Wr; C = xr1; Nc = 256; cof = (cbi - 2) * 128; }
    else              { B = Wp; C = proj; Nc = 128; cof = 0; bias = bp; }
    int tid = threadIdx.x;
    int rowb = blockIdx.y * 128;
    int ra = (tid / 16) * 4, cb = (tid % 16) * 4;
    {
        int ar = tid >> 1, ak = (tid & 1) * 16;
        const float* ap = &x[(size_t)(rowb + ar) * 32 + ak];
        #pragma unroll
        for (int q = 0; q < 4; ++q) {
            float4 v = *(const float4*)(ap + q * 4);
            As[ak + q*4 + 0][ar] = v.x; As[ak + q*4 + 1][ar] = v.y;
            As[ak + q*4 + 2][ar] = v.z; As[ak + q*4 + 3][ar] = v.w;
        }
        int bk = tid >> 3, bc = (tid & 7) * 16;
        const float* bpp = &B[(size_t)bk * Nc + cof + bc];
        #pragma unroll
        for (int q = 0; q < 4; ++q)
            *(float4*)&Bs[bk][bc + q*4] = *(const float4*)(bpp + q*4);
    }
    __syncthreads();
    float acc[8][8] = {};
    #pragma unroll
    for (int kk = 0; kk < 32; ++kk) {
        float4 a0 = *(const float4*)&As[kk][ra];
        float4 a1 = *(const float4*)&As[kk][ra + 64];
        float4 b0 = *(const float4*)&Bs[kk][cb];
        float4 b1 = *(const float4*)&Bs[kk][cb + 64];
        float av[8] = {a0.x,a0.y,a0.z,a0.w,a1.x,a1.y,a1.z,a1.w};
        float bv[8] = {b0.x,b0.y,b0.z,b0.w,b1.x,b1.y,b1.z,b1.w};
        #pragma unroll
        for (int i = 0; i < 8; ++i)
            #pragma unroll
            for (int j = 0; j < 8; ++j)
                acc[i][j] += av[i] * bv[j];
    }
    #pragma unroll
    for (int i = 0; i < 8; ++i) {
        int rloc = ra + (i & 3) + (i >> 2) * 64;
        #pragma unroll
        for (int jg = 0; jg < 2; ++jg)
            #pragma unroll
            for (int j = 0; j < 4; ++j) {
                int col = cb + jg * 64 + j;
                float v = acc[i][jg * 4 + j];
                if (bias) v += bias[col];
                C[(size_t)(rowb + rloc) * Nc + cof + col] = v;
            }
    }
}

// ---------------- GEMM 2: elu(bn(h1)) @ {W2l, W2r} -> xl2, xr2 (bn fused on A-load) ----------------
__global__ __launch_bounds__(256) void k_gemm_gat2(
    const float* __restrict__ h1, const float* __restrict__ Wl, const float* __restrict__ Wr,
    const float* __restrict__ scale1, const float* __restrict__ shift1,
    float* __restrict__ xl2, float* __restrict__ xr2)
{
    __shared__ float As[32][128];
    __shared__ float Bs[32][132];
    const float* B = blockIdx.x ? Wr : Wl;
    float* C = blockIdx.x ? xr2 : xl2;
    int tid = threadIdx.x;
    int rowb = blockIdx.y * 128;
    int ra = (tid / 16) * 4, cb = (tid % 16) * 4;
    int ar = tid >> 1, ak = (tid & 1) * 16;
    int bk = tid >> 3, bc = (tid & 7) * 16;
    int g = (rowb + ar) / NN_;
    const float* scp = scale1 + g * 256;
    const float* shp = shift1 + g * 256;
    float acc[8][8] = {};
    for (int k0 = 0; k0 < 256; k0 += 32) {
        {
            const float* ap = &h1[(size_t)(rowb + ar) * 256 + k0 + ak];
            #pragma unroll
            for (int q = 0; q < 4; ++q) {
                float4 av = *(const float4*)(ap + q * 4);
                float4 sv = *(const float4*)&scp[k0 + ak + q * 4];
                float4 tv = *(const float4*)&shp[k0 + ak + q * 4];
                float v0 = av.x * sv.x + tv.x; v0 = v0 > 0.f ? v0 : expm1f(v0);
                float v1 = av.y * sv.y + tv.y; v1 = v1 > 0.f ? v1 : expm1f(v1);
                float v2 = av.z * sv.z + tv.z; v2 = v2 > 0.f ? v2 : expm1f(v2);
                float v3 = av.w * sv.w + tv.w; v3 = v3 > 0.f ? v3 : expm1f(v3);
                As[ak + q*4 + 0][ar] = v0; As[ak + q*4 + 1][ar] = v1;
                As[ak + q*4 + 2][ar] = v2; As[ak + q*4 + 3][ar] = v3;
            }
            const float* bpp = &B[(size_t)(k0 + bk) * 128 + bc];
            #pragma unroll
            for (int q = 0; q < 4; ++q)
                *(float4*)&Bs[bk][bc + q*4] = *(const float4*)(bpp + q*4);
        }
        __syncthreads();
        #pragma unroll
        for (int kk = 0; kk < 32; ++kk) {
            float4 a0 = *(const float4*)&As[kk][ra];
            float4 a1 = *(const float4*)&As[kk][ra + 64];
            float4 b0 = *(const float4*)&Bs[kk][cb];
            float4 b1 = *(const float4*)&Bs[kk][cb + 64];
            float av[8] = {a0.x,a0.y,a0.z,a0.w,a1.x,a1.y,a1.z,a1.w};
            float bv[8] = {b0.x,b0.y,b0.z,b0.w,b1.x,b1.y,b1.z,b1.w};
            #pragma unroll
            for (int i = 0; i < 8; ++i)
                #pragma unroll
                for (int j = 0; j < 8; ++j)
                    acc[i][j] += av[i] * bv[j];
        }
        __syncthreads();
    }
    #pragma unroll
    for (int i = 0; i < 8; ++i) {
        int rloc = ra + (i & 3) + (i >> 2) * 64;
        #pragma unroll
        for (int jg = 0; jg < 2; ++jg)
            #pragma unroll
            for (int j = 0; j < 4; ++j)
                C[(size_t)(rowb + rloc) * 128 + cb + jg * 64 + j] = acc[i][jg * 4 + j];
    }
}

// ---------------- fused GATv2: logits + per-wave online softmax + aggregate ----------------
template<int NH, int CD>
__global__ void k_gat(const float* __restrict__ xl, const float* __restrict__ xr,
                      const float* __restrict__ att, const int* __restrict__ ei,
                      const int* __restrict__ rowptr, const int* __restrict__ eids,
                      const float* __restrict__ bias, float* __restrict__ out)
{
    const int BD = NH * CD;
    const int NW = BD / 64;
    int g = blockIdx.x / NN_, dst = blockIdx.x % NN_;
    int tid = threadIdx.x, lane = tid & 63, w = tid >> 6;
    int h = tid / CD;
    int rs = rowptr[dst], re = rowptr[dst + 1];
    __shared__ float xrs[BD], atts[BD];
    __shared__ float lgl[64][NH];
    __shared__ int   srcs[64];
    __shared__ float wm[NW][NH], wsum[NW][NH];
    size_t gbase = (size_t)g * NN_;
    xrs[tid]  = xr[(gbase + dst) * BD + tid];
    atts[tid] = att[tid];
    float accM = -1e30f, accS = 0.f, acc = 0.f;
    for (int base = rs; base < re; base += 64) {
        int nl = min(64, re - base);
        __syncthreads();
        if (tid < nl) {
            int eid = eids[base + tid];
            srcs[tid] = eid < E0_ ? ei[eid] : eid - E0_;
        }
        __syncthreads();
        float mw[NH], sw[NH];
        #pragma unroll
        for (int hh = 0; hh < NH; ++hh) { mw[hh] = -1e30f; sw[hh] = 0.f; }
        for (int i = w; i < nl; i += NW) {
            const float* pl = &xl[(gbase + srcs[i]) * BD];
            #pragma unroll
            for (int hh = 0; hh < NH; ++hh) {
                float s = 0.f;
                #pragma unroll
                for (int c = lane; c < CD; c += 64) {
                    float v = pl[hh * CD + c] + xrs[hh * CD + c];
                    v = v > 0.f ? v : 0.2f * v;
                    s = fmaf(v, atts[hh * CD + c], s);
                }
                #pragma unroll
                for (int o = 32; o; o >>= 1) s += __shfl_xor(s, o);
                if (lane == 0) lgl[i][hh] = s;
                float nm = fmaxf(mw[hh], s);
                sw[hh] = sw[hh] * __expf(mw[hh] - nm) + __expf(s - nm);
                mw[hh] = nm;
            }
        }
        if (lane < NH) { wm[w][lane] = mw[lane]; wsum[w][lane] = sw[lane]; }
        __syncthreads();
        float mc[NH], sc[NH];
        #pragma unroll
        for (int hh = 0; hh < NH; ++hh) mc[hh] = -1e30f;
        #pragma unroll
        for (int ww = 0; ww < NW; ++ww)
            #pragma unroll
            for (int hh = 0; hh < NH; ++hh) mc[hh] = fmaxf(mc[hh], wm[ww][hh]);
        #pragma unroll
        for (int hh = 0; hh < NH; ++hh) sc[hh] = 0.f;
        #pragma unroll
        for (int ww = 0; ww < NW; ++ww)
            #pragma unroll
            for (int hh = 0; hh < NH; ++hh) sc[hh] += wsum[ww][hh] * __expf(wm[ww][hh] - mc[hh]);
        if (tid < nl) {
            #pragma unroll
            for (int hh = 0; hh < NH; ++hh) lgl[tid][hh] = __expf(lgl[tid][hh] - mc[hh]);
        }
        __syncthreads();
        float nM = fmaxf(accM, mc[h]);
        float f_old = __expf(accM - nM), f_new = __expf(mc[h] - nM);
        acc *= f_old;
        accS = accS * f_old + sc[h] * f_new;
        accM = nM;
        int i = 0;
        for (; i + 4 <= nl; i += 4) {
            float e0 = lgl[i][h], e1 = lgl[i+1][h], e2 = lgl[i+2][h], e3 = lgl[i+3][h];
            const float* r0 = &xl[(gbase + srcs[i])   * BD];
            const float* r1 = &xl[(gbase + srcs[i+1]) * BD];
            const float* r2 = &xl[(gbase + srcs[i+2]) * BD];
            const float* r3 = &xl[(gbase + srcs[i+3]) * BD];
            acc += f_new * (e0 * r0[tid] + e1 * r1[tid] + e2 * r2[tid] + e3 * r3[tid]);
        }
        for (; i < nl; ++i)
            acc += f_new * lgl[i][h] * xl[(gbase + srcs[i]) * BD + tid];
    }
    out[(gbase + dst) * BD + tid] = acc / (accS + 1e-16f) + bias[tid];
}

// ---------------- BatchNorm stats -> fused scale/shift ----------------
template<int C>
__global__ __launch_bounds__(C * 4) void k_bnstats(
    const float* __restrict__ h, const float* __restrict__ gamma, const float* __restrict__ beta,
    float* __restrict__ scale, float* __restrict__ shift)
{
    int g = blockIdx.x;
    int c = threadIdx.x % C, q = threadIdx.x / C;
    __shared__ float ps[4][C], pss[4][C];
    float s = 0.f, ss = 0.f;
    for (int n = q * 125; n < (q + 1) * 125; ++n) {
        float v = h[((size_t)g * NN_ + n) * C + c];
        s += v; ss += v * v;
    }
    ps[q][c] = s; pss[q][c] = ss;
    __syncthreads();
    if (q == 0) {
        #pragma unroll
        for (int qq = 1; qq < 4; ++qq) { s += ps[qq][c]; ss += pss[qq][c]; }
        float m = s * (1.f / NN_);
        float var = ss * (1.f / NN_) - m * m;
        float r = rsqrtf(var + 1e-5f);
        float sc = r * gamma[c];
        scale[g * C + c] = sc;
        shift[g * C + c] = beta[c] - m * sc;
    }
}

// ---------------- BN2 apply + ELU + residual add (vectorized) ----------------
__global__ void k_bn_elu_add4(const float* __restrict__ h2, const float* __restrict__ scale2,
                              const float* __restrict__ shift2, const float* __restrict__ proj,
                              float* __restrict__ hres) {
    int i4 = blockIdx.x * blockDim.x + threadIdx.x;
    if (i4 >= G_ * NN_ * HD_ / 4) return;
    int base = i4 * 4;
    int c = base & 127;
    int g = base / (NN_ * HD_);
    float4 hv = *(const float4*)&h2[base];
    float4 sc = *(const float4*)&scale2[g * 128 + c];
    float4 sh = *(const float4*)&shift2[g * 128 + c];
    float4 pv = *(const float4*)&proj[base];
    float v0 = hv.x * sc.x + sh.x; v0 = (v0 > 0.f ? v0 : expm1f(v0)) + pv.x;
    float v1 = hv.y * sc.y + sh.y; v1 = (v1 > 0.f ? v1 : expm1f(v1)) + pv.y;
    float v2 = hv.z * sc.z + sh.z; v2 = (v2 > 0.f ? v2 : expm1f(v2)) + pv.z;
    float v3 = hv.w * sc.w + sh.w; v3 = (v3 > 0.f ? v3 : expm1f(v3)) + pv.w;
    *(float4*)&hres[base] = make_float4(v0, v1, v2, v3);
}

// ---------------- persistent LSTM via split-bf16 MFMA ----------------
// 125 blocks x 512 threads (8 waves). Block owns 16 rows. Wave w owns gate cols [w*64, w*64+64).
// A = [h(128) | x(128)] fp32 in LDS, converted per-fragment to bf16 hi/lo.
// gates = Ah*Wh + Al*Wh + Ah*Wl  (AlWl term ~2^-18 relative, dropped).
#define LROW 132
#define GROW 524

__device__ __forceinline__ void mfma_gates(
    const float* __restrict__ A0, const float* __restrict__ A1,   // LDS [16][LROW]: k<128 / k>=128
    const unsigned short* __restrict__ WB,                         // hi at 0, lo at +131072
    float* __restrict__ gl, const float* __restrict__ bb,          // bb[4] per-lane bias
    int lane, int w)
{
    f32x4 acc[4] = {{0.f,0.f,0.f,0.f},{0.f,0.f,0.f,0.f},{0.f,0.f,0.f,0.f},{0.f,0.f,0.f,0.f}};
    const int row = lane & 15, kg = lane >> 4;
    const int cb = w * 64 + (lane & 15);
    #pragma unroll 2
    for (int kt = 0; kt < 8; ++kt) {
        const float* S = (kt < 4) ? A0 : A1;
        int koff = (kt & 3) * 32 + kg * 8;
        float4 a0 = *(const float4*)&S[row * LROW + koff];
        float4 a1 = *(const float4*)&S[row * LROW + koff + 4];
        float av[8] = {a0.x, a0.y, a0.z, a0.w, a1.x, a1.y, a1.z, a1.w};
        union { unsigned short u[8]; bf16x8 v; } ah, al;
        #pragma unroll
        for (int j = 0; j < 8; ++j) {
            unsigned short hb = f2bf(av[j]);
            ah.u[j] = hb;
            al.u[j] = f2bf(av[j] - bf2f(hb));
        }
        const unsigned short* ph = WB + ((size_t)(kt * 4 + kg) * 512 + cb) * 8;
        #pragma unroll
        for (int nt = 0; nt < 4; ++nt) {
            bf16x8 bh = *(const bf16x8*)(ph + nt * 128);            // +16 cols * 8
            bf16x8 bl = *(const bf16x8*)(ph + 131072 + nt * 128);
            acc[nt] = __builtin_amdgcn_mfma_f32_16x16x32_bf16(ah.v, bh, acc[nt], 0, 0, 0);
            acc[nt] = __builtin_amdgcn_mfma_f32_16x16x32_bf16(al.v, bh, acc[nt], 0, 0, 0);
            acc[nt] = __builtin_amdgcn_mfma_f32_16x16x32_bf16(ah.v, bl, acc[nt], 0, 0, 0);
        }
    }
    // C/D layout: col = lane&15, row = (lane>>4)*4 + reg   [m89-verified]
    const int crow = (lane >> 4) * 4;
    #pragma unroll
    for (int nt = 0; nt < 4; ++nt)
        #pragma unroll
        for (int r = 0; r < 4; ++r)
            gl[(crow + r) * GROW + w * 64 + nt * 16 + (lane & 15)] = acc[nt][r] + bb[nt];
}

__device__ __forceinline__ void cell_mfma(
    const float* __restrict__ gl, float* __restrict__ cs, float* __restrict__ hs,
    int ur, int uc0)
{
    float4 gi = *(const float4*)&gl[ur * GROW + uc0];
    float4 gf = *(const float4*)&gl[ur * GROW + 128 + uc0];
    float4 gg = *(const float4*)&gl[ur * GROW + 256 + uc0];
    float4 go = *(const float4*)&gl[ur * GROW + 384 + uc0];
    float4 co = *(const float4*)&cs[ur * LROW + uc0];
    const float* gif = (const float*)&gi; const float* gff = (const float*)&gf;
    const float* ggf = (const float*)&gg; const float* gof = (const float*)&go;
    const float* cof = (const float*)&co;
    float cv[4], hv[4];
    #pragma unroll
    for (int j = 0; j < 4; ++j) {
        float iv = fsig(gif[j]);
        float fv = fsig(gff[j]);
        float gv = ftanh(ggf[j]);
        float ov = fsig(gof[j]);
        float cn = fv * cof[j] + iv * gv;
        cv[j] = cn;
        hv[j] = ov * ftanh(cn);
    }
    *(float4*)&cs[ur * LROW + uc0] = make_float4(cv[0], cv[1], cv[2], cv[3]);
    *(float4*)&hs[ur * LROW + uc0] = make_float4(hv[0], hv[1], hv[2], hv[3]);
}

__global__ __launch_bounds__(512) void k_lstm_all(
    const float* __restrict__ hres,
    const unsigned short* __restrict__ WB0, const unsigned short* __restrict__ WB1,
    const float* __restrict__ bih0, const float* __restrict__ bhh0,
    const float* __restrict__ bih1, const float* __restrict__ bhh1,
    const float* __restrict__ fcW1, const float* __restrict__ fcb1,
    const float* __restrict__ fcW2, const float* __restrict__ fcb2,
    float* __restrict__ out)
{
    __shared__ float h1s[16 * LROW], c1s[16 * LROW], h2s[16 * LROW], c2s[16 * LROW];
    __shared__ float xs[16 * LROW];
    __shared__ float gl[16 * GROW];
    int tid = threadIdx.x, lane = tid & 63, w = tid >> 6;
    int r0 = blockIdx.x * 16;
    for (int i = tid; i < 16 * LROW; i += 512) {
        h1s[i] = 0.f; c1s[i] = 0.f; h2s[i] = 0.f; c2s[i] = 0.f;
    }
    float bb0[4], bb1[4];
    #pragma unroll
    for (int nt = 0; nt < 4; ++nt) {
        int c = w * 64 + nt * 16 + (lane & 15);
        bb0[nt] = bih0[c] + bhh0[c];
        bb1[nt] = bih1[c] + bhh1[c];
    }
    const int ur = tid >> 5, uc0 = (tid & 31) * 4;
    {   // stage x_0
        *(float4*)&xs[ur * LROW + uc0] = *(const float4*)&hres[(size_t)((r0 + ur) * 16 + 0) * 128 + uc0];
    }
    __syncthreads();
    for (int t = 0; t < TT_; ++t) {
        mfma_gates(h1s, xs, WB0, gl, bb0, lane, w);
        __syncthreads();
        cell_mfma(gl, c1s, h1s, ur, uc0);
        __syncthreads();
        mfma_gates(h2s, h1s, WB1, gl, bb1, lane, w);
        __syncthreads();
        cell_mfma(gl, c2s, h2s, ur, uc0);
        if (t < TT_ - 1) {
            *(float4*)&xs[ur * LROW + uc0] =
                *(const float4*)&hres[(size_t)((r0 + ur) * 16 + t + 1) * 128 + uc0];
        }
        __syncthreads();
    }
    // FC head: relu(h2 @ W1 + b1) @ W2 + b2 ; 32 lanes per row, 2 cols each
    int fr = tid >> 5, j = tid & 31;
    float s0 = fcb1[j], s1 = fcb1[j + 32];
    #pragma unroll 8
    for (int k = 0; k < 128; ++k) {
        float hv = h2s[fr * LROW + k];
        s0 += hv * fcW1[k * 64 + j];
        s1 += hv * fcW1[k * 64 + j + 32];
    }
    float p = fmaxf(s0, 0.f) * fcW2[j] + fmaxf(s1, 0.f) * fcW2[j + 32];
    #pragma unroll
    for (int o = 16; o; o >>= 1) p += __shfl_xor(p, o);
    if (j == 0) out[r0 + fr] = p + fcb2[0];
}

// ---------------- workspace layout (float offsets) ----------------
static const size_t OFF_XL1  = 0;           // 8,192,000
static const size_t OFF_XR1  = 8192000;     // 8,192,000
static const size_t OFF_H1   = 16384000;    // 8,192,000
static const size_t OFF_XL2  = 24576000;    // 4,096,000
static const size_t OFF_XR2  = 28672000;    // 4,096,000
static const size_t OFF_H2   = 32768000;    // 4,096,000
static const size_t OFF_PRJ  = 36864000;    // 4,096,000
static const size_t OFF_HRES = 40960000;    // 4,096,000
static const size_t OFF_SC1  = 45056000;    // 16384
static const size_t OFF_SH1  = 45072384;    // 16384
static const size_t OFF_SC2  = 45088768;    // 8192
static const size_t OFF_SH2  = 45096960;    // 8192
static const size_t OFF_WT0  = 45105152;    // 131072 floats = 262144 ushorts (hi|lo)
static const size_t OFF_WT1  = 45236224;    // 131072 floats
static const size_t OFF_INT  = 45367296;    // int region

extern "C" void kernel_launch(void* const* d_in, const int* in_sizes, int n_in,
                              void* d_out, int out_size, void* d_ws, size_t ws_size,
                              hipStream_t stream) {
    const float* x        = (const float*)d_in[0];
    const int*   ei       = (const int*)  d_in[1];
    const float* W_proj   = (const float*)d_in[2];
    const float* b_proj   = (const float*)d_in[3];
    const float* gat1_Wl  = (const float*)d_in[4];
    const float* gat1_Wr  = (const float*)d_in[5];
    const float* gat1_att = (const float*)d_in[6];
    const float* gat1_b   = (const float*)d_in[7];
    const float* bn1_g    = (const float*)d_in[8];
    const float* bn1_b    = (const float*)d_in[9];
    const float* gat2_Wl  = (const float*)d_in[10];
    const float* gat2_Wr  = (const float*)d_in[11];
    const float* gat2_att = (const float*)d_in[12];
    const float* gat2_b   = (const float*)d_in[13];
    const float* bn2_g    = (const float*)d_in[14];
    const float* bn2_b    = (const float*)d_in[15];
    const float* Wih0     = (const float*)d_in[16];
    const float* Whh0     = (const float*)d_in[17];
    const float* bih0     = (const float*)d_in[18];
    const float* bhh0     = (const float*)d_in[19];
    const float* Wih1     = (const float*)d_in[20];
    const float* Whh1     = (const float*)d_in[21];
    const float* bih1     = (const float*)d_in[22];
    const float* bhh1     = (const float*)d_in[23];
    const float* fc_W1    = (const float*)d_in[24];
    const float* fc_b1    = (const float*)d_in[25];
    const float* fc_W2    = (const float*)d_in[26];
    const float* fc_b2    = (const float*)d_in[27];
    float* out = (float*)d_out;

    float* ws = (float*)d_ws;
    float* xl1  = ws + OFF_XL1;
    float* xr1  = ws + OFF_XR1;
    float* h1   = ws + OFF_H1;
    float* xl2  = ws + OFF_XL2;
    float* xr2  = ws + OFF_XR2;
    float* h2   = ws + OFF_H2;
    float* proj = ws + OFF_PRJ;
    float* hres = ws + OFF_HRES;
    float* sc1  = ws + OFF_SC1;
    float* sh1  = ws + OFF_SH1;
    float* sc2  = ws + OFF_SC2;
    float* sh2  = ws + OFF_SH2;
    unsigned short* WB0 = (unsigned short*)(ws + OFF_WT0);
    unsigned short* WB1 = (unsigned short*)(ws + OFF_WT1);

    int* ibase  = (int*)(ws + OFF_INT);
    int* deg    = ibase;
    int* rowptr = ibase + 512;
    int* cursor = ibase + 1024;
    int* eids   = ibase + 1536;

    // ---- CSR build + weight prepack ----
    hipMemsetAsync(deg, 0, NN_ * sizeof(int), stream);
    k_deg<<<(EP_ + 255) / 256, 256, 0, stream>>>(ei, deg);
    k_scan<<<1, 1, 0, stream>>>(deg, rowptr, cursor);
    k_fill<<<(EP_ + 255) / 256, 256, 0, stream>>>(ei, cursor, eids);
    k_wt<<<dim3(512, 2), 256, 0, stream>>>(Whh0, Wih0, Whh1, Wih1, WB0, WB1);

    // ---- GAT1 ----
    k_gemm_gat1<<<dim3(5, 250), 256, 0, stream>>>(x, gat1_Wl, gat1_Wr, W_proj, b_proj, xl1, xr1, proj);
    k_gat<2, HD_><<<G_ * NN_, 256, 0, stream>>>(xl1, xr1, gat1_att, ei, rowptr, eids, gat1_b, h1);
    k_bnstats<C1_><<<G_, C1_ * 4, 0, stream>>>(h1, bn1_g, bn1_b, sc1, sh1);

    // ---- GAT2 (bn1+elu fused into A-load) ----
    k_gemm_gat2<<<dim3(2, 250), 256, 0, stream>>>(h1, gat2_Wl, gat2_Wr, sc1, sh1, xl2, xr2);
    k_gat<1, HD_><<<G_ * NN_, 128, 0, stream>>>(xl2, xr2, gat2_att, ei, rowptr, eids, gat2_b, h2);
    k_bnstats<HD_><<<G_, HD_ * 4, 0, stream>>>(h2, bn2_g, bn2_b, sc2, sh2);

    // ---- BN2 + ELU + residual ----
    k_bn_elu_add4<<<(G_ * NN_ * HD_ / 4 + 255) / 256, 256, 0, stream>>>(h2, sc2, sh2, proj, hres);

    // ---- persistent LSTM (both layers, all steps, MFMA) + FC head ----
    k_lstm_all<<<125, 512, 0, stream>>>(hres, WB0, WB1, bih0, bhh0, bih1, bhh1,
                                        fc_W1, fc_b1, fc_W2, fc_b2, out);
}

// Round 6
// 632.082 us; speedup vs baseline: 1.6775x; 1.0780x over previous
//
#include <hip/hip_runtime.h>
#include <hip/hip_bf16.h>
#include <math.h>

#define G_   64      // B*T graphs
#define NN_  500     // nodes
#define FIN_ 32
#define HD_  128
#define C1_  256     // HEADS*HD
#define E0_  8000
#define EP_  8500    // E0 + self loops
#define TT_  16
#define NR_  2000    // B*N lstm rows

typedef __attribute__((ext_vector_type(8))) short bf16x8;
typedef __attribute__((ext_vector_type(4))) float f32x4;

__device__ __forceinline__ float fsig(float x)  { return 1.f / (1.f + __expf(-x)); }
__device__ __forceinline__ float ftanh(float x) {
    float e = __expf(fminf(fmaxf(2.f * x, -30.f), 30.f));
    return (e - 1.f) / (e + 1.f);
}
__device__ __forceinline__ unsigned short f2bf(float f) {
    unsigned int u = __float_as_uint(f);
    return (unsigned short)((u + 0x7FFFu + ((u >> 16) & 1u)) >> 16);
}
__device__ __forceinline__ float bf2f(unsigned short h) {
    return __uint_as_float(((unsigned int)h) << 16);
}

// ---------------- CSR build (by dst) ----------------
__global__ void k_deg(const int* __restrict__ ei, int* __restrict__ deg) {
    int e = blockIdx.x * blockDim.x + threadIdx.x;
    if (e >= EP_) return;
    int dst = e < E0_ ? ei[E0_ + e] : e - E0_;
    atomicAdd(&deg[dst], 1);
}
__global__ void k_scan(const int* __restrict__ deg, int* __restrict__ rowptr, int* __restrict__ cursor) {
    if (threadIdx.x == 0 && blockIdx.x == 0) {
        int acc = 0;
        for (int i = 0; i < NN_; ++i) { rowptr[i] = acc; cursor[i] = acc; acc += deg[i]; }
        rowptr[NN_] = acc;
    }
}
__global__ void k_fill(const int* __restrict__ ei, int* __restrict__ cursor, int* __restrict__ eids) {
    int e = blockIdx.x * blockDim.x + threadIdx.x;
    if (e >= EP_) return;
    int dst = e < E0_ ? ei[E0_ + e] : e - E0_;
    int pos = atomicAdd(&cursor[dst], 1);
    eids[pos] = e;
}

// ---------------- LSTM weight prepack: split-bf16, MFMA B-fragment layout ----------------
// WB layout per layer: [hi: 131072][lo: 131072] ushort.
// index(k, col) = ((k>>3)*512 + col)*8 + (k&7), k = [Whh k<128 | Wih k-128], col in [0,512).
__global__ void k_wt(const float* __restrict__ Whh0, const float* __restrict__ Wih0,
                     const float* __restrict__ Whh1, const float* __restrict__ Wih1,
                     unsigned short* __restrict__ WB0, unsigned short* __restrict__ WB1) {
    int layer = blockIdx.y;
    int n = blockIdx.x * 256 + threadIdx.x;   // 0..131071
    const float* Wh = layer ? Whh1 : Whh0;
    const float* Wi = layer ? Wih1 : Wih0;
    unsigned short* WB = layer ? WB1 : WB0;
    int j = n & 7, col = (n >> 3) & 511, kb8 = n >> 12;
    int k = kb8 * 8 + j;
    float w = (k < 128) ? Wh[(size_t)col * 128 + k] : Wi[(size_t)col * 128 + (k - 128)];
    unsigned short h = f2bf(w);
    WB[n] = h;
    WB[131072 + n] = f2bf(w - bf2f(h));
}

// ---------------- GEMM 1: x[32000,32] @ {Wl,Wr,Wp} -> xl1, xr1, proj ----------------
__global__ __launch_bounds__(256) void k_gemm_gat1(
    const float* __restrict__ x, const float* __restrict__ Wl, const float* __restrict__ Wr,
    const float* __restrict__ Wp, const float* __restrict__ bp,
    float* __restrict__ xl1, float* __restrict__ xr1, float* __restrict__ proj)
{
    __shared__ float As[32][128];
    __shared__ float Bs[32][132];
    int cbi = blockIdx.x;
    const float* B; float* C; const float* bias = nullptr; int Nc, cof;
    if (cbi < 2)      { B = Wl; C = xl1; Nc = 256; cof = cbi * 128; }
    else if (cbi < 4) { B = Wr; C = xr1; Nc = 256; cof = (cbi - 2) * 128; }
    else              { B = Wp; C = proj; Nc = 128; cof = 0; bias = bp; }
    int tid = threadIdx.x;
    int rowb = blockIdx.y * 128;
    int ra = (tid / 16) * 4, cb = (tid % 16) * 4;
    {
        int ar = tid >> 1, ak = (tid & 1) * 16;
        const float* ap = &x[(size_t)(rowb + ar) * 32 + ak];
        #pragma unroll
        for (int q = 0; q < 4; ++q) {
            float4 v = *(const float4*)(ap + q * 4);
            As[ak + q*4 + 0][ar] = v.x; As[ak + q*4 + 1][ar] = v.y;
            As[ak + q*4 + 2][ar] = v.z; As[ak + q*4 + 3][ar] = v.w;
        }
        int bk = tid >> 3, bc = (tid & 7) * 16;
        const float* bpp = &B[(size_t)bk * Nc + cof + bc];
        #pragma unroll
        for (int q = 0; q < 4; ++q)
            *(float4*)&Bs[bk][bc + q*4] = *(const float4*)(bpp + q*4);
    }
    __syncthreads();
    float acc[8][8] = {};
    #pragma unroll
    for (int kk = 0; kk < 32; ++kk) {
        float4 a0 = *(const float4*)&As[kk][ra];
        float4 a1 = *(const float4*)&As[kk][ra + 64];
        float4 b0 = *(const float4*)&Bs[kk][cb];
        float4 b1 = *(const float4*)&Bs[kk][cb + 64];
        float av[8] = {a0.x,a0.y,a0.z,a0.w,a1.x,a1.y,a1.z,a1.w};
        float bv[8] = {b0.x,b0.y,b0.z,b0.w,b1.x,b1.y,b1.z,b1.w};
        #pragma unroll
        for (int i = 0; i < 8; ++i)
            #pragma unroll
            for (int j = 0; j < 8; ++j)
                acc[i][j] += av[i] * bv[j];
    }
    #pragma unroll
    for (int i = 0; i < 8; ++i) {
        int rloc = ra + (i & 3) + (i >> 2) * 64;
        #pragma unroll
        for (int jg = 0; jg < 2; ++jg)
            #pragma unroll
            for (int j = 0; j < 4; ++j) {
                int col = cb + jg * 64 + j;
                float v = acc[i][jg * 4 + j];
                if (bias) v += bias[col];
                C[(size_t)(rowb + rloc) * Nc + cof + col] = v;
            }
    }
}

// ---------------- GEMM 2: elu(bn(h1)) @ {W2l, W2r} -> xl2, xr2 (bn fused on A-load) ----------------
__global__ __launch_bounds__(256) void k_gemm_gat2(
    const float* __restrict__ h1, const float* __restrict__ Wl, const float* __restrict__ Wr,
    const float* __restrict__ scale1, const float* __restrict__ shift1,
    float* __restrict__ xl2, float* __restrict__ xr2)
{
    __shared__ float As[32][128];
    __shared__ float Bs[32][132];
    const float* B = blockIdx.x ? Wr : Wl;
    float* C = blockIdx.x ? xr2 : xl2;
    int tid = threadIdx.x;
    int rowb = blockIdx.y * 128;
    int ra = (tid / 16) * 4, cb = (tid % 16) * 4;
    int ar = tid >> 1, ak = (tid & 1) * 16;
    int bk = tid >> 3, bc = (tid & 7) * 16;
    int g = (rowb + ar) / NN_;
    const float* scp = scale1 + g * 256;
    const float* shp = shift1 + g * 256;
    float acc[8][8] = {};
    for (int k0 = 0; k0 < 256; k0 += 32) {
        {
            const float* ap = &h1[(size_t)(rowb + ar) * 256 + k0 + ak];
            #pragma unroll
            for (int q = 0; q < 4; ++q) {
                float4 av = *(const float4*)(ap + q * 4);
                float4 sv = *(const float4*)&scp[k0 + ak + q * 4];
                float4 tv = *(const float4*)&shp[k0 + ak + q * 4];
                float v0 = av.x * sv.x + tv.x; v0 = v0 > 0.f ? v0 : expm1f(v0);
                float v1 = av.y * sv.y + tv.y; v1 = v1 > 0.f ? v1 : expm1f(v1);
                float v2 = av.z * sv.z + tv.z; v2 = v2 > 0.f ? v2 : expm1f(v2);
                float v3 = av.w * sv.w + tv.w; v3 = v3 > 0.f ? v3 : expm1f(v3);
                As[ak + q*4 + 0][ar] = v0; As[ak + q*4 + 1][ar] = v1;
                As[ak + q*4 + 2][ar] = v2; As[ak + q*4 + 3][ar] = v3;
            }
            const float* bpp = &B[(size_t)(k0 + bk) * 128 + bc];
            #pragma unroll
            for (int q = 0; q < 4; ++q)
                *(float4*)&Bs[bk][bc + q*4] = *(const float4*)(bpp + q*4);
        }
        __syncthreads();
        #pragma unroll
        for (int kk = 0; kk < 32; ++kk) {
            float4 a0 = *(const float4*)&As[kk][ra];
            float4 a1 = *(const float4*)&As[kk][ra + 64];
            float4 b0 = *(const float4*)&Bs[kk][cb];
            float4 b1 = *(const float4*)&Bs[kk][cb + 64];
            float av[8] = {a0.x,a0.y,a0.z,a0.w,a1.x,a1.y,a1.z,a1.w};
            float bv[8] = {b0.x,b0.y,b0.z,b0.w,b1.x,b1.y,b1.z,b1.w};
            #pragma unroll
            for (int i = 0; i < 8; ++i)
                #pragma unroll
                for (int j = 0; j < 8; ++j)
                    acc[i][j] += av[i] * bv[j];
        }
        __syncthreads();
    }
    #pragma unroll
    for (int i = 0; i < 8; ++i) {
        int rloc = ra + (i & 3) + (i >> 2) * 64;
        #pragma unroll
        for (int jg = 0; jg < 2; ++jg)
            #pragma unroll
            for (int j = 0; j < 4; ++j)
                C[(size_t)(rowb + rloc) * 128 + cb + jg * 64 + j] = acc[i][jg * 4 + j];
    }
}

// ---------------- fused GATv2: logits + per-wave online softmax + aggregate ----------------
template<int NH, int CD>
__global__ void k_gat(const float* __restrict__ xl, const float* __restrict__ xr,
                      const float* __restrict__ att, const int* __restrict__ ei,
                      const int* __restrict__ rowptr, const int* __restrict__ eids,
                      const float* __restrict__ bias, float* __restrict__ out)
{
    const int BD = NH * CD;
    const int NW = BD / 64;
    int g = blockIdx.x / NN_, dst = blockIdx.x % NN_;
    int tid = threadIdx.x, lane = tid & 63, w = tid >> 6;
    int h = tid / CD;
    int rs = rowptr[dst], re = rowptr[dst + 1];
    __shared__ float xrs[BD], atts[BD];
    __shared__ float lgl[64][NH];
    __shared__ int   srcs[64];
    __shared__ float wm[NW][NH], wsum[NW][NH];
    size_t gbase = (size_t)g * NN_;
    xrs[tid]  = xr[(gbase + dst) * BD + tid];
    atts[tid] = att[tid];
    float accM = -1e30f, accS = 0.f, acc = 0.f;
    for (int base = rs; base < re; base += 64) {
        int nl = min(64, re - base);
        __syncthreads();
        if (tid < nl) {
            int eid = eids[base + tid];
            srcs[tid] = eid < E0_ ? ei[eid] : eid - E0_;
        }
        __syncthreads();
        float mw[NH], sw[NH];
        #pragma unroll
        for (int hh = 0; hh < NH; ++hh) { mw[hh] = -1e30f; sw[hh] = 0.f; }
        for (int i = w; i < nl; i += NW) {
            const float* pl = &xl[(gbase + srcs[i]) * BD];
            #pragma unroll
            for (int hh = 0; hh < NH; ++hh) {
                float s = 0.f;
                #pragma unroll
                for (int c = lane; c < CD; c += 64) {
                    float v = pl[hh * CD + c] + xrs[hh * CD + c];
                    v = v > 0.f ? v : 0.2f * v;
                    s = fmaf(v, atts[hh * CD + c], s);
                }
                #pragma unroll
                for (int o = 32; o; o >>= 1) s += __shfl_xor(s, o);
                if (lane == 0) lgl[i][hh] = s;
                float nm = fmaxf(mw[hh], s);
                sw[hh] = sw[hh] * __expf(mw[hh] - nm) + __expf(s - nm);
                mw[hh] = nm;
            }
        }
        if (lane < NH) { wm[w][lane] = mw[lane]; wsum[w][lane] = sw[lane]; }
        __syncthreads();
        float mc[NH], sc[NH];
        #pragma unroll
        for (int hh = 0; hh < NH; ++hh) mc[hh] = -1e30f;
        #pragma unroll
        for (int ww = 0; ww < NW; ++ww)
            #pragma unroll
            for (int hh = 0; hh < NH; ++hh) mc[hh] = fmaxf(mc[hh], wm[ww][hh]);
        #pragma unroll
        for (int hh = 0; hh < NH; ++hh) sc[hh] = 0.f;
        #pragma unroll
        for (int ww = 0; ww < NW; ++ww)
            #pragma unroll
            for (int hh = 0; hh < NH; ++hh) sc[hh] += wsum[ww][hh] * __expf(wm[ww][hh] - mc[hh]);
        if (tid < nl) {
            #pragma unroll
            for (int hh = 0; hh < NH; ++hh) lgl[tid][hh] = __expf(lgl[tid][hh] - mc[hh]);
        }
        __syncthreads();
        float nM = fmaxf(accM, mc[h]);
        float f_old = __expf(accM - nM), f_new = __expf(mc[h] - nM);
        acc *= f_old;
        accS = accS * f_old + sc[h] * f_new;
        accM = nM;
        int i = 0;
        for (; i + 4 <= nl; i += 4) {
            float e0 = lgl[i][h], e1 = lgl[i+1][h], e2 = lgl[i+2][h], e3 = lgl[i+3][h];
            const float* r0 = &xl[(gbase + srcs[i])   * BD];
            const float* r1 = &xl[(gbase + srcs[i+1]) * BD];
            const float* r2 = &xl[(gbase + srcs[i+2]) * BD];
            const float* r3 = &xl[(gbase + srcs[i+3]) * BD];
            acc += f_new * (e0 * r0[tid] + e1 * r1[tid] + e2 * r2[tid] + e3 * r3[tid]);
        }
        for (; i < nl; ++i)
            acc += f_new * lgl[i][h] * xl[(gbase + srcs[i]) * BD + tid];
    }
    out[(gbase + dst) * BD + tid] = acc / (accS + 1e-16f) + bias[tid];
}

// ---------------- BatchNorm stats -> fused scale/shift ----------------
template<int C>
__global__ __launch_bounds__(C * 4) void k_bnstats(
    const float* __restrict__ h, const float* __restrict__ gamma, const float* __restrict__ beta,
    float* __restrict__ scale, float* __restrict__ shift)
{
    int g = blockIdx.x;
    int c = threadIdx.x % C, q = threadIdx.x / C;
    __shared__ float ps[4][C], pss[4][C];
    float s = 0.f, ss = 0.f;
    for (int n = q * 125; n < (q + 1) * 125; ++n) {
        float v = h[((size_t)g * NN_ + n) * C + c];
        s += v; ss += v * v;
    }
    ps[q][c] = s; pss[q][c] = ss;
    __syncthreads();
    if (q == 0) {
        #pragma unroll
        for (int qq = 1; qq < 4; ++qq) { s += ps[qq][c]; ss += pss[qq][c]; }
        float m = s * (1.f / NN_);
        float var = ss * (1.f / NN_) - m * m;
        float r = rsqrtf(var + 1e-5f);
        float sc = r * gamma[c];
        scale[g * C + c] = sc;
        shift[g * C + c] = beta[c] - m * sc;
    }
}

// ---------------- BN2 apply + ELU + residual add (vectorized) ----------------
__global__ void k_bn_elu_add4(const float* __restrict__ h2, const float* __restrict__ scale2,
                              const float* __restrict__ shift2, const float* __restrict__ proj,
                              float* __restrict__ hres) {
    int i4 = blockIdx.x * blockDim.x + threadIdx.x;
    if (i4 >= G_ * NN_ * HD_ / 4) return;
    int base = i4 * 4;
    int c = base & 127;
    int g = base / (NN_ * HD_);
    float4 hv = *(const float4*)&h2[base];
    float4 sc = *(const float4*)&scale2[g * 128 + c];
    float4 sh = *(const float4*)&shift2[g * 128 + c];
    float4 pv = *(const float4*)&proj[base];
    float v0 = hv.x * sc.x + sh.x; v0 = (v0 > 0.f ? v0 : expm1f(v0)) + pv.x;
    float v1 = hv.y * sc.y + sh.y; v1 = (v1 > 0.f ? v1 : expm1f(v1)) + pv.y;
    float v2 = hv.z * sc.z + sh.z; v2 = (v2 > 0.f ? v2 : expm1f(v2)) + pv.z;
    float v3 = hv.w * sc.w + sh.w; v3 = (v3 > 0.f ? v3 : expm1f(v3)) + pv.w;
    *(float4*)&hres[base] = make_float4(v0, v1, v2, v3);
}

// ---------------- persistent LSTM via split-bf16 MFMA, fragment-resident LDS ----------------
// 125 blocks x 512 threads (8 waves). Block owns 16 rows; wave w owns gate cols [w*64,(w+1)*64).
// h/x live in LDS as bf16 hi/lo in MFMA A-fragment order: frag unit u = (k>>3)*16 + row,
// holding k = (k>>3)*8 .. +7. Split is done ONCE (at cell update / staging), not per wave.
#define GROW 516

__device__ __forceinline__ void mfma_gates_frag(
    const bf16x8* __restrict__ Fh_hi, const bf16x8* __restrict__ Fh_lo,   // K first half (h)
    const bf16x8* __restrict__ Fx_hi, const bf16x8* __restrict__ Fx_lo,   // K second half (x)
    const unsigned short* __restrict__ WB, float* __restrict__ gl,
    const float* __restrict__ bb, int lane, int w)
{
    f32x4 acc[4] = {{0.f,0.f,0.f,0.f},{0.f,0.f,0.f,0.f},{0.f,0.f,0.f,0.f},{0.f,0.f,0.f,0.f}};
    const int row = lane & 15, kg = lane >> 4;
    const int cb = w * 64 + row;
    #pragma unroll 2
    for (int kt = 0; kt < 8; ++kt) {
        const bf16x8* Hh = (kt < 4) ? Fh_hi : Fx_hi;
        const bf16x8* Hl = (kt < 4) ? Fh_lo : Fx_lo;
        int fu = ((kt & 3) * 4 + kg) * 16 + row;
        bf16x8 ah = Hh[fu];
        bf16x8 al = Hl[fu];
        const unsigned short* ph = WB + ((size_t)(kt * 4 + kg) * 512 + cb) * 8;
        #pragma unroll
        for (int nt = 0; nt < 4; ++nt) {
            bf16x8 bh = *(const bf16x8*)(ph + nt * 128);
            bf16x8 bl = *(const bf16x8*)(ph + 131072 + nt * 128);
            acc[nt] = __builtin_amdgcn_mfma_f32_16x16x32_bf16(ah, bh, acc[nt], 0, 0, 0);
            acc[nt] = __builtin_amdgcn_mfma_f32_16x16x32_bf16(al, bh, acc[nt], 0, 0, 0);
            acc[nt] = __builtin_amdgcn_mfma_f32_16x16x32_bf16(ah, bl, acc[nt], 0, 0, 0);
        }
    }
    // C/D layout: col = lane&15, row = (lane>>4)*4 + reg
    const int crow = kg * 4;
    #pragma unroll
    for (int nt = 0; nt < 4; ++nt)
        #pragma unroll
        for (int r = 0; r < 4; ++r)
            gl[(crow + r) * GROW + w * 64 + nt * 16 + row] = acc[nt][r] + bb[nt];
}

// cell update by threads t256 in [0,256): r = t256&15, kb8 = t256>>4 (8 consecutive k).
__device__ __forceinline__ void cell_frag(
    const float* __restrict__ gl, float* __restrict__ cs,
    bf16x8* __restrict__ Hhi, bf16x8* __restrict__ Hlo, int t256)
{
    int r = t256 & 15, kb8 = t256 >> 4;
    const float* gr = gl + r * GROW + kb8 * 8;
    float* cp = cs + (r * 128 + kb8 * 8);
    union { unsigned short u[8]; bf16x8 v; } hh, hl;
    float cv[8];
    #pragma unroll
    for (int j = 0; j < 8; ++j) {
        float iv = fsig(gr[j]);
        float fv = fsig(gr[128 + j]);
        float gv = ftanh(gr[256 + j]);
        float ov = fsig(gr[384 + j]);
        float cn = fv * cp[j] + iv * gv;
        cv[j] = cn;
        float hv = ov * ftanh(cn);
        unsigned short hb = f2bf(hv);
        hh.u[j] = hb;
        hl.u[j] = f2bf(hv - bf2f(hb));
    }
    #pragma unroll
    for (int j = 0; j < 8; ++j) cp[j] = cv[j];
    Hhi[t256] = hh.v;
    Hlo[t256] = hl.v;
}

// x staging by threads t256 in [0,256): convert hres row-slice to bf16 hi/lo frags.
__device__ __forceinline__ void stage_x_frag(
    const float* __restrict__ src_row,    // &hres[((r0+r)*16 + t)*128]
    bf16x8* __restrict__ Xhi, bf16x8* __restrict__ Xlo, int t256)
{
    int kb8 = t256 >> 4;
    const float* sp = src_row + kb8 * 8;
    union { unsigned short u[8]; bf16x8 v; } hh, hl;
    #pragma unroll
    for (int j = 0; j < 8; ++j) {
        float v = sp[j];
        unsigned short hb = f2bf(v);
        hh.u[j] = hb;
        hl.u[j] = f2bf(v - bf2f(hb));
    }
    Xhi[t256] = hh.v;
    Xlo[t256] = hl.v;
}

__global__ __launch_bounds__(512) void k_lstm_all(
    const float* __restrict__ hres,
    const unsigned short* __restrict__ WB0, const unsigned short* __restrict__ WB1,
    const float* __restrict__ bih0, const float* __restrict__ bhh0,
    const float* __restrict__ bih1, const float* __restrict__ bhh1,
    const float* __restrict__ fcW1, const float* __restrict__ fcb1,
    const float* __restrict__ fcW2, const float* __restrict__ fcb2,
    float* __restrict__ out)
{
    __shared__ bf16x8 h1h[256], h1l[256], h2h[256], h2l[256], xh[256], xlo[256];
    __shared__ float c1s[16 * 128], c2s[16 * 128];
    __shared__ float gl[16 * GROW];
    int tid = threadIdx.x, lane = tid & 63, w = tid >> 6;
    int r0 = blockIdx.x * 16;

    // zero-init h frags + c state
    if (tid < 256) {
        bf16x8 z = {0,0,0,0,0,0,0,0};
        h1h[tid] = z; h1l[tid] = z; h2h[tid] = z; h2l[tid] = z;
    }
    for (int i = tid; i < 16 * 128; i += 512) { c1s[i] = 0.f; c2s[i] = 0.f; }

    float bb0[4], bb1[4];
    #pragma unroll
    for (int nt = 0; nt < 4; ++nt) {
        int c = w * 64 + nt * 16 + (lane & 15);
        bb0[nt] = bih0[c] + bhh0[c];
        bb1[nt] = bih1[c] + bhh1[c];
    }
    if (tid >= 256) {   // stage x_0
        int t256 = tid - 256;
        int r = t256 & 15;
        stage_x_frag(&hres[(size_t)((r0 + r) * 16 + 0) * 128], xh, xlo, t256);
    }
    __syncthreads();
    for (int t = 0; t < TT_; ++t) {
        mfma_gates_frag(h1h, h1l, xh, xlo, WB0, gl, bb0, lane, w);
        __syncthreads();
        if (tid < 256) cell_frag(gl, c1s, h1h, h1l, tid);
        __syncthreads();
        mfma_gates_frag(h2h, h2l, h1h, h1l, WB1, gl, bb1, lane, w);
        __syncthreads();
        if (tid < 256) {
            cell_frag(gl, c2s, h2h, h2l, tid);
        } else if (t < TT_ - 1) {   // stage x_{t+1} concurrently (x dead until next gates1)
            int t256 = tid - 256;
            int r = t256 & 15;
            stage_x_frag(&hres[(size_t)((r0 + r) * 16 + t + 1) * 128], xh, xlo, t256);
        }
        __syncthreads();
    }
    // FC head: relu(h2 @ W1 + b1) @ W2 + b2 ; 32 lanes per row, 2 cols each
    const unsigned short* h2hu = (const unsigned short*)h2h;
    const unsigned short* h2lu = (const unsigned short*)h2l;
    int fr = tid >> 5, j = tid & 31;
    float s0 = fcb1[j], s1 = fcb1[j + 32];
    #pragma unroll 8
    for (int k = 0; k < 128; ++k) {
        int fi = ((k >> 3) * 16 + fr) * 8 + (k & 7);
        float hv = bf2f(h2hu[fi]) + bf2f(h2lu[fi]);
        s0 += hv * fcW1[k * 64 + j];
        s1 += hv * fcW1[k * 64 + j + 32];
    }
    float p = fmaxf(s0, 0.f) * fcW2[j] + fmaxf(s1, 0.f) * fcW2[j + 32];
    #pragma unroll
    for (int o = 16; o; o >>= 1) p += __shfl_xor(p, o);
    if (j == 0) out[r0 + fr] = p + fcb2[0];
}

// ---------------- workspace layout (float offsets) ----------------
static const size_t OFF_XL1  = 0;           // 8,192,000
static const size_t OFF_XR1  = 8192000;     // 8,192,000
static const size_t OFF_H1   = 16384000;    // 8,192,000
static const size_t OFF_XL2  = 24576000;    // 4,096,000
static const size_t OFF_XR2  = 28672000;    // 4,096,000
static const size_t OFF_H2   = 32768000;    // 4,096,000
static const size_t OFF_PRJ  = 36864000;    // 4,096,000
static const size_t OFF_HRES = 40960000;    // 4,096,000
static const size_t OFF_SC1  = 45056000;    // 16384
static const size_t OFF_SH1  = 45072384;    // 16384
static const size_t OFF_SC2  = 45088768;    // 8192
static const size_t OFF_SH2  = 45096960;    // 8192
static const size_t OFF_WT0  = 45105152;    // 131072 floats = 262144 ushorts (hi|lo)
static const size_t OFF_WT1  = 45236224;    // 131072 floats
static const size_t OFF_INT  = 45367296;    // int region

extern "C" void kernel_launch(void* const* d_in, const int* in_sizes, int n_in,
                              void* d_out, int out_size, void* d_ws, size_t ws_size,
                              hipStream_t stream) {
    const float* x        = (const float*)d_in[0];
    const int*   ei       = (const int*)  d_in[1];
    const float* W_proj   = (const float*)d_in[2];
    const float* b_proj   = (const float*)d_in[3];
    const float* gat1_Wl  = (const float*)d_in[4];
    const float* gat1_Wr  = (const float*)d_in[5];
    const float* gat1_att = (const float*)d_in[6];
    const float* gat1_b   = (const float*)d_in[7];
    const float* bn1_g    = (const float*)d_in[8];
    const float* bn1_b    = (const float*)d_in[9];
    const float* gat2_Wl  = (const float*)d_in[10];
    const float* gat2_Wr  = (const float*)d_in[11];
    const float* gat2_att = (const float*)d_in[12];
    const float* gat2_b   = (const float*)d_in[13];
    const float* bn2_g    = (const float*)d_in[14];
    const float* bn2_b    = (const float*)d_in[15];
    const float* Wih0     = (const float*)d_in[16];
    const float* Whh0     = (const float*)d_in[17];
    const float* bih0     = (const float*)d_in[18];
    const float* bhh0     = (const float*)d_in[19];
    const float* Wih1     = (const float*)d_in[20];
    const float* Whh1     = (const float*)d_in[21];
    const float* bih1     = (const float*)d_in[22];
    const float* bhh1     = (const float*)d_in[23];
    const float* fc_W1    = (const float*)d_in[24];
    const float* fc_b1    = (const float*)d_in[25];
    const float* fc_W2    = (const float*)d_in[26];
    const float* fc_b2    = (const float*)d_in[27];
    float* out = (float*)d_out;

    float* ws = (float*)d_ws;
    float* xl1  = ws + OFF_XL1;
    float* xr1  = ws + OFF_XR1;
    float* h1   = ws + OFF_H1;
    float* xl2  = ws + OFF_XL2;
    float* xr2  = ws + OFF_XR2;
    float* h2   = ws + OFF_H2;
    float* proj = ws + OFF_PRJ;
    float* hres = ws + OFF_HRES;
    float* sc1  = ws + OFF_SC1;
    float* sh1  = ws + OFF_SH1;
    float* sc2  = ws + OFF_SC2;
    float* sh2  = ws + OFF_SH2;
    unsigned short* WB0 = (unsigned short*)(ws + OFF_WT0);
    unsigned short* WB1 = (unsigned short*)(ws + OFF_WT1);

    int* ibase  = (int*)(ws + OFF_INT);
    int* deg    = ibase;
    int* rowptr = ibase + 512;
    int* cursor = ibase + 1024;
    int* eids   = ibase + 1536;

    // ---- CSR build + weight prepack ----
    hipMemsetAsync(deg, 0, NN_ * sizeof(int), stream);
    k_deg<<<(EP_ + 255) / 256, 256, 0, stream>>>(ei, deg);
    k_scan<<<1, 1, 0, stream>>>(deg, rowptr, cursor);
    k_fill<<<(EP_ + 255) / 256, 256, 0, stream>>>(ei, cursor, eids);
    k_wt<<<dim3(512, 2), 256, 0, stream>>>(Whh0, Wih0, Whh1, Wih1, WB0, WB1);

    // ---- GAT1 ----
    k_gemm_gat1<<<dim3(5, 250), 256, 0, stream>>>(x, gat1_Wl, gat1_Wr, W_proj, b_proj, xl1, xr1, proj);
    k_gat<2, HD_><<<G_ * NN_, 256, 0, stream>>>(xl1, xr1, gat1_att, ei, rowptr, eids, gat1_b, h1);
    k_bnstats<C1_><<<G_, C1_ * 4, 0, stream>>>(h1, bn1_g, bn1_b, sc1, sh1);

    // ---- GAT2 (bn1+elu fused into A-load) ----
    k_gemm_gat2<<<dim3(2, 250), 256, 0, stream>>>(h1, gat2_Wl, gat2_Wr, sc1, sh1, xl2, xr2);
    k_gat<1, HD_><<<G_ * NN_, 128, 0, stream>>>(xl2, xr2, gat2_att, ei, rowptr, eids, gat2_b, h2);
    k_bnstats<HD_><<<G_, HD_ * 4, 0, stream>>>(h2, bn2_g, bn2_b, sc2, sh2);

    // ---- BN2 + ELU + residual ----
    k_bn_elu_add4<<<(G_ * NN_ * HD_ / 4 + 255) / 256, 256, 0, stream>>>(h2, sc2, sh2, proj, hres);

    // ---- persistent LSTM (both layers, all steps, MFMA) + FC head ----
    k_lstm_all<<<125, 512, 0, stream>>>(hres, WB0, WB1, bih0, bhh0, bih1, bhh1,
                                        fc_W1, fc_b1, fc_W2, fc_b2, out);
}